// Round 3
// baseline (1268.134 us; speedup 1.0000x reference)
//
#include <hip/hip_runtime.h>
#include <math.h>

#define NB 8
#define NC 192
#define NH 128
#define NW 128
#define HW 16384
#define NQ 576
#define NHID 510
#define NHIDP 512
#define NG2 1020
#define NG2P 1024

// band geometry: 4 bands x 32 rows, 1-row halo each side -> 34-slot buffers
#define BROWS 32
#define BSLOTS 34
#define BPIX (BSLOTS * NW)      // 4352 pixels per batch in band buffer
#define BIPIX (BROWS * NW)      // 4096 interior pixels per batch

typedef unsigned short u16;
typedef short s16x8 __attribute__((ext_vector_type(8)));
typedef float f32x4 __attribute__((ext_vector_type(4)));

#define MFMA_BF16(a, b, c) __builtin_amdgcn_mfma_f32_16x16x32_bf16((a), (b), (c), 0, 0, 0)

__device__ __forceinline__ u16 f2bf(float f) {
  union { float f; unsigned u; } v; v.f = f;
  unsigned r = v.u + 0x7fffu + ((v.u >> 16) & 1u);
  return (u16)(r >> 16);
}
__device__ __forceinline__ float bf2f(u16 h) {
  union { unsigned u; float f; } v; v.u = ((unsigned)h) << 16; return v.f;
}
__device__ __forceinline__ float lo2f(unsigned u) {
  union { unsigned u; float f; } v; v.u = u << 16; return v.f;
}
__device__ __forceinline__ float hi2f(unsigned u) {
  union { unsigned u; float f; } v; v.u = u & 0xffff0000u; return v.f;
}

// ---------------------------------------------------------------------------
// Weight prep: fp32 -> bf16 (ffn_in padded to 1024 rows, ffn_out to 512 cols)
// ---------------------------------------------------------------------------
__global__ void k_prep(const float* __restrict__ wq, const float* __restrict__ wfi,
                       const float* __restrict__ wfo,
                       u16* __restrict__ oq, u16* __restrict__ ofi, u16* __restrict__ ofo) {
  const int n1 = NQ * NC, n2 = NG2P * NC, n3 = NC * NHIDP;
  for (int i = blockIdx.x * blockDim.x + threadIdx.x; i < n1 + n2 + n3;
       i += gridDim.x * blockDim.x) {
    if (i < n1) {
      oq[i] = f2bf(wq[i]);
    } else if (i < n1 + n2) {
      int j = i - n1; int row = j / NC;
      u16 v = 0;
      if (row < NG2) v = f2bf(wfi[j]);
      ofi[j] = v;
    } else {
      int j = i - n1 - n2; int row = j >> 9, col = j & 511;
      u16 v = 0;
      if (col < NHID) v = f2bf(wfo[row * NHID + col]);
      ofo[j] = v;
    }
  }
}

// ---------------------------------------------------------------------------
// Context adapters: temp_total (b,4) and v_gate (b,192)
// ---------------------------------------------------------------------------
__global__ void k_ctx(const float* __restrict__ ce, const float* __restrict__ taw1,
                      const float* __restrict__ tab1, const float* __restrict__ taw2,
                      const float* __restrict__ tab2, const float* __restrict__ vgw,
                      const float* __restrict__ vgb, const float* __restrict__ btemp,
                      float* __restrict__ tempt, float* __restrict__ vg) {
  int b = blockIdx.x, t = threadIdx.x;
  __shared__ float sce[256];
  __shared__ float shid[48];
  sce[t] = ce[b * 256 + t];
  __syncthreads();
  if (t < 48) {
    float s = tab1[t];
    for (int j = 0; j < 256; j++) s = fmaf(taw1[t * 256 + j], sce[j], s);
    shid[t] = fmaxf(s, 0.f);
  }
  __syncthreads();
  if (t < 4) {
    float s = tab2[t];
    for (int j = 0; j < 48; j++) s = fmaf(taw2[t * 48 + j], shid[j], s);
    float sg = 1.f / (1.f + expf(-s));
    tempt[b * 4 + t] = btemp[t] * (sg * 2.f + 0.5f);
  }
  if (t < 192) {
    float s = vgb[t];
    for (int j = 0; j < 256; j++) s = fmaf(vgw[t * 256 + j], sce[j], s);
    vg[b * 192 + t] = 1.f / (1.f + expf(-s));
  }
}

// ---------------------------------------------------------------------------
// Banded fused per-pixel LayerNorm (192 ch) + 1x1-conv GEMM (bf16 MFMA).
// ---------------------------------------------------------------------------
__global__ __launch_bounds__(256, 2)
void k_ln_gemm_band(const float* __restrict__ in, const float* __restrict__ lnw,
                    const float* __restrict__ lnb, const u16* __restrict__ wbf,
                    u16* __restrict__ out, int nchunks, int row_start, int slot0) {
  __shared__ u16 Xn[64 * 200];
  __shared__ u16 Wc[64 * 200];
  __shared__ float red[512];
  __shared__ float stats[128];
  int t = threadIdx.x;
  int lane = t & 63, wv = t >> 6;
  int bpb = gridDim.x >> 3;                 // blocks per batch = nrows*2
  int b = blockIdx.x / bpb;
  int rb = blockIdx.x - b * bpb;
  int gpx0 = row_start * NW + rb * 64;      // global pixel base
  int opx0 = slot0 * NW + rb * 64;          // band-local pixel base
  const float* xp = in + (size_t)b * NC * HW + gpx0 + lane;
  float vals[48];
  float s = 0.f, s2 = 0.f;
#pragma unroll
  for (int j = 0; j < 48; j++) {
    float v = xp[(size_t)(wv * 48 + j) * HW];
    vals[j] = v; s += v; s2 = fmaf(v, v, s2);
  }
  red[wv * 64 + lane] = s;
  red[256 + wv * 64 + lane] = s2;
  __syncthreads();
  if (t < 64) {
    float m = 0.f, q = 0.f;
#pragma unroll
    for (int k = 0; k < 4; k++) { m += red[k * 64 + t]; q += red[256 + k * 64 + t]; }
    m *= (1.f / 192.f);
    float var = q * (1.f / 192.f) - m * m;
    stats[t] = m; stats[64 + t] = rsqrtf(var + 1e-5f);
  }
  __syncthreads();
  float mu = stats[lane], rs = stats[64 + lane];
#pragma unroll
  for (int j = 0; j < 48; j += 2) {
    int c = wv * 48 + j;
    float xa = (vals[j] - mu) * rs * lnw[c] + lnb[c];
    float xb = (vals[j + 1] - mu) * rs * lnw[c + 1] + lnb[c + 1];
    *(unsigned*)&Xn[lane * 200 + c] = (unsigned)f2bf(xa) | ((unsigned)f2bf(xb) << 16);
  }
  int r = lane & 15, grp = lane >> 4;
  int ostride = nchunks << 6;
  for (int nc = 0; nc < nchunks; nc++) {
    __syncthreads();
    for (int i = t; i < 1536; i += 256) {
      int row = i / 24, sg = i % 24;
      *(s16x8*)&Wc[row * 200 + sg * 8] =
          *(const s16x8*)&wbf[(size_t)(nc * 64 + row) * 192 + sg * 8];
    }
    __syncthreads();
    f32x4 z = {0.f, 0.f, 0.f, 0.f};
    f32x4 acc0 = z, acc1 = z, acc2 = z, acc3 = z;
#pragma unroll
    for (int ks = 0; ks < 6; ks++) {
      int k0 = ks * 32 + grp * 8;
      s16x8 a = *(s16x8*)&Xn[(wv * 16 + r) * 200 + k0];
      acc0 = MFMA_BF16(a, *(s16x8*)&Wc[r * 200 + k0], acc0);
      acc1 = MFMA_BF16(a, *(s16x8*)&Wc[(16 + r) * 200 + k0], acc1);
      acc2 = MFMA_BF16(a, *(s16x8*)&Wc[(32 + r) * 200 + k0], acc2);
      acc3 = MFMA_BF16(a, *(s16x8*)&Wc[(48 + r) * 200 + k0], acc3);
    }
    u16* op = out + ((size_t)b * BPIX + opx0 + wv * 16 + grp * 4) * ostride + nc * 64 + r;
#pragma unroll
    for (int i = 0; i < 4; i++) {
      op[(size_t)i * ostride] = f2bf(acc0[i]);
      op[(size_t)i * ostride + 16] = f2bf(acc1[i]);
      op[(size_t)i * ostride + 32] = f2bf(acc2[i]);
      op[(size_t)i * ostride + 48] = f2bf(acc3[i]);
    }
  }
}

// ---------------------------------------------------------------------------
// Banded depthwise 3x3 on qkv band buffer [B][BPIX][576] bf16.
// ---------------------------------------------------------------------------
__global__ __launch_bounds__(256, 4)
void k_dw_attn_band(const u16* __restrict__ qb_band, const float* __restrict__ wdw,
                    u16* __restrict__ qkb, u16* __restrict__ vpm,
                    float* __restrict__ ssq, int r0) {
  __shared__ u16 Hl[6 * 18 * 64];
  __shared__ float sred[8 * 64];
  int t = threadIdx.x;
  int cc = blockIdx.x % 9;
  int rem = blockIdx.x / 9;        // 512 values
  int b = rem >> 6; int r2 = rem & 63;
  int h0l = (r2 >> 3) * 4, w0 = (r2 & 7) * 16;   // band-local interior row, col
  int c0 = cc * 64;
  const s16x8 z8 = {0, 0, 0, 0, 0, 0, 0, 0};
  for (int i = t; i < 864; i += 256) {
    int px = i >> 3, sg = i & 7;
    int hh = px / 18, ww = px % 18;
    int slot = h0l + hh;                 // in [0, 34)
    int gh = r0 - 1 + slot;
    int gw = w0 - 1 + ww;
    s16x8 v = z8;
    if (gh >= 0 && gh < NH && gw >= 0 && gw < NW)
      v = *(const s16x8*)&qb_band[((size_t)b * BPIX + slot * NW + gw) * NQ + c0 + sg * 8];
    *(s16x8*)&Hl[(hh * 18 + ww) * 64 + sg * 8] = v;
  }
  __syncthreads();
  int cp = t & 31, psub = t >> 5;
  int pr = psub >> 1, pc0 = (psub & 1) * 8;
  int gc = c0 + 2 * cp;
  float wg0[9], wg1[9];
#pragma unroll
  for (int q = 0; q < 9; q++) { wg0[q] = wdw[gc * 9 + q]; wg1[q] = wdw[(gc + 1) * 9 + q]; }
  bool isv = (c0 >= 384);
  float sq0 = 0.f, sq1 = 0.f;
  s16x8 ov0 = z8, ov1 = z8;
#pragma unroll
  for (int j = 0; j < 8; j++) {
    int pc = pc0 + j;
    float a0 = 0.f, a1 = 0.f;
#pragma unroll
    for (int dr = 0; dr < 3; dr++)
#pragma unroll
      for (int dc = 0; dc < 3; dc++) {
        unsigned u = *(const unsigned*)&Hl[((pr + dr) * 18 + pc + dc) * 64 + 2 * cp];
        a0 = fmaf(lo2f(u), wg0[dr * 3 + dc], a0);
        a1 = fmaf(hi2f(u), wg1[dr * 3 + dc], a1);
      }
    u16 u0 = f2bf(a0), u1 = f2bf(a1);
    if (isv) {
      int gp = (r0 + h0l + pr) * NW + w0 + pc;   // global pixel
      *(unsigned*)&vpm[((size_t)b * HW + gp) * 192 + (gc - 384)] =
          (unsigned)u0 | ((unsigned)u1 << 16);
    } else {
      ov0[j] = (short)u0; ov1[j] = (short)u1;
      float f0 = bf2f(u0), f1 = bf2f(u1);
      sq0 = fmaf(f0, f0, sq0); sq1 = fmaf(f1, f1, sq1);
    }
  }
  if (!isv) {
    int lpx = (h0l + pr) * NW + w0 + pc0;        // band-local pixel
    *(s16x8*)&qkb[((size_t)b * 384 + gc) * BIPIX + lpx] = ov0;
    *(s16x8*)&qkb[((size_t)b * 384 + gc + 1) * BIPIX + lpx] = ov1;
    sred[psub * 64 + 2 * cp] = sq0;
    sred[psub * 64 + 2 * cp + 1] = sq1;
    __syncthreads();
    if (t < 64) {
      float sa = 0.f;
#pragma unroll
      for (int p8 = 0; p8 < 8; p8++) sa += sred[p8 * 64 + t];
      atomicAdd(&ssq[b * 384 + c0 + t], sa);
    }
  }
}

// ---------------------------------------------------------------------------
// attn_raw[b,h,c,d] += sum_{band px} q[c,px]*k[d,px]  (MFMA, K split 4 ways)
// ---------------------------------------------------------------------------
__global__ __launch_bounds__(256, 2)
void k_attn_band(const u16* __restrict__ qkb, float* __restrict__ attn) {
  __shared__ float par[4 * 2304];
  int t = threadIdx.x;
  int lane = t & 63, wv = t >> 6;
  int r = lane & 15, grp = lane >> 4;
  int bh = blockIdx.x >> 2, kc = blockIdx.x & 3;
  int b = bh >> 2, h = bh & 3;
  const u16* qb = qkb + ((size_t)b * 384 + h * 48) * BIPIX;
  const u16* kb = qkb + ((size_t)b * 384 + 192 + h * 48) * BIPIX;
  f32x4 z = {0.f, 0.f, 0.f, 0.f};
  f32x4 acc[3][3];
#pragma unroll
  for (int i = 0; i < 3; i++)
#pragma unroll
    for (int j = 0; j < 3; j++) acc[i][j] = z;
  int kbase = kc * 1024 + wv * 256 + grp * 8;
#pragma unroll 2
  for (int ks = 0; ks < 8; ks++) {
    int k0 = kbase + ks * 32;
    s16x8 af[3], bf[3];
#pragma unroll
    for (int mt = 0; mt < 3; mt++) af[mt] = *(const s16x8*)&qb[(size_t)(mt * 16 + r) * BIPIX + k0];
#pragma unroll
    for (int nt = 0; nt < 3; nt++) bf[nt] = *(const s16x8*)&kb[(size_t)(nt * 16 + r) * BIPIX + k0];
#pragma unroll
    for (int mt = 0; mt < 3; mt++)
#pragma unroll
      for (int nt = 0; nt < 3; nt++) acc[mt][nt] = MFMA_BF16(af[mt], bf[nt], acc[mt][nt]);
  }
#pragma unroll
  for (int mt = 0; mt < 3; mt++)
#pragma unroll
    for (int nt = 0; nt < 3; nt++)
#pragma unroll
      for (int i = 0; i < 4; i++)
        par[wv * 2304 + (mt * 16 + grp * 4 + i) * 48 + nt * 16 + r] = acc[mt][nt][i];
  __syncthreads();
  float* ag = attn + (size_t)bh * 2304;
  for (int i = t; i < 2304; i += 256)
    atomicAdd(&ag[i], par[i] + par[2304 + i] + par[4608 + i] + par[6912 + i]);
}

// ---------------------------------------------------------------------------
// Softmax over d with q/k norms, scale, temp; fold v_gate in (in place)
// ---------------------------------------------------------------------------
__global__ void k_softmax(float* __restrict__ attn, const float* __restrict__ ssq,
                          const float* __restrict__ tempt, const float* __restrict__ vg) {
  int bh = blockIdx.x, b = bh >> 2, h = bh & 3;
  int t = threadIdx.x;  // 64
  __shared__ float srk[48], svg[48];
  if (t < 48) {
    float nk = sqrtf(ssq[b * 384 + 192 + h * 48 + t]);
    srk[t] = 1.f / fmaxf(nk, 1e-12f);
    svg[t] = vg[b * 192 + h * 48 + t];
  }
  __syncthreads();
  if (t < 48) {
    float nq = sqrtf(ssq[b * 384 + h * 48 + t]);
    float rq = 1.f / fmaxf(nq, 1e-12f);
    float sc = 0.14433756729740643f * tempt[b * 4 + h] * rq;
    float* row = attn + (size_t)bh * 2304 + t * 48;
    float l[48]; float mx = -1e30f;
#pragma unroll
    for (int d = 0; d < 48; d++) { l[d] = row[d] * srk[d] * sc; mx = fmaxf(mx, l[d]); }
    float ss = 0.f;
#pragma unroll
    for (int d = 0; d < 48; d++) { l[d] = expf(l[d] - mx); ss += l[d]; }
    float inv = 1.f / ss;
#pragma unroll
    for (int d = 0; d < 48; d++) row[d] = l[d] * inv * svg[d];
  }
}

// ---------------------------------------------------------------------------
// W_D[b] = [ w_proj @ blockdiag(attn') | w_proj ]  (192 x 384 bf16 per batch)
// ---------------------------------------------------------------------------
__global__ __launch_bounds__(256)
void k_wd(const float* __restrict__ attn, const float* __restrict__ wp,
          u16* __restrict__ wdg) {
  __shared__ float am[4 * 48 * 48];
  int b = blockIdx.x >> 3, oc = blockIdx.x & 7;
  int t = threadIdx.x;
  const float* ag = attn + (size_t)b * 4 * 2304;
  for (int i = t; i < 9216; i += 256) am[i] = ag[i];
  __syncthreads();
  u16* wdb = wdg + (size_t)b * 192 * 384;
  for (int idx = t; idx < 24 * 384; idx += 256) {
    int oo = idx / 384, j = idx % 384;
    int o = oc * 24 + oo;
    float val;
    if (j < 192) {
      int hj = j / 48, dj = j % 48;
      const float* wpo = wp + o * 192 + hj * 48;
      const float* ap = am + hj * 2304 + dj;
      float sa = 0.f;
#pragma unroll
      for (int c = 0; c < 48; c++) sa = fmaf(wpo[c], ap[c * 48], sa);
      val = sa;
    } else {
      val = wp[o * 192 + (j - 192)];
    }
    wdb[o * 384 + j] = f2bf(val);
  }
}

// ---------------------------------------------------------------------------
// x2 = x + W_D @ [v ; dwconv3x3_local(v)] per 4x16 pixel tile (MFMA, K=384)
// T14 async-stage: the 48 per-thread x-residual loads (100 MB stream, 43% of
// this kernel's HBM bytes) are issued in the PROLOGUE (pinned before the
// first __syncthreads) and consumed in the epilogue, so the x stream
// overlaps the halo/dwconv/MFMA phases instead of serializing at the tail.
// ---------------------------------------------------------------------------
__global__ __launch_bounds__(256, 2)
void k_proj(const u16* __restrict__ vpm, const float* __restrict__ wl,
            const u16* __restrict__ wdg, const float* __restrict__ x,
            float* __restrict__ x2) {
  __shared__ u16 Hl[6 * 18 * 64];
  __shared__ u16 Xl[64 * 392];
  int t = threadIdx.x;
  int b = blockIdx.x >> 8; int r2 = blockIdx.x & 255;
  int h0 = (r2 >> 3) * 4, w0 = (r2 & 7) * 16;
  int cp = t & 31, psub = t >> 5;
  int pr = psub >> 1, pc0 = (psub & 1) * 8;
  int lane = t & 63, wv = t >> 6;
  int r = lane & 15, grp = lane >> 4;
  // --- prologue: issue residual loads early (can't sink past __syncthreads)
  float xres[3][4][4];
#pragma unroll
  for (int mt = 0; mt < 3; mt++)
#pragma unroll
    for (int nt = 0; nt < 4; nt++) {
      size_t base = ((size_t)b * NC + wv * 48 + mt * 16 + grp * 4) * HW +
                    (h0 + nt) * NW + w0 + r;
#pragma unroll
      for (int i = 0; i < 4; i++) xres[mt][nt][i] = x[base + (size_t)i * HW];
    }
  const s16x8 z8 = {0, 0, 0, 0, 0, 0, 0, 0};
  for (int c3 = 0; c3 < 3; c3++) {
    int c0 = c3 * 64;
    __syncthreads();
    for (int i = t; i < 864; i += 256) {
      int px = i >> 3, sg = i & 7;
      int hh = px / 18, ww = px % 18;
      int gh = h0 - 1 + hh, gw = w0 - 1 + ww;
      s16x8 v = z8;
      if (gh >= 0 && gh < NH && gw >= 0 && gw < NW)
        v = *(const s16x8*)&vpm[((size_t)b * HW + gh * NW + gw) * 192 + c0 + sg * 8];
      *(s16x8*)&Hl[(hh * 18 + ww) * 64 + sg * 8] = v;
    }
    __syncthreads();
    int gc = c0 + 2 * cp;
    float wg0[9], wg1[9];
#pragma unroll
    for (int q = 0; q < 9; q++) { wg0[q] = wl[gc * 9 + q]; wg1[q] = wl[(gc + 1) * 9 + q]; }
#pragma unroll
    for (int j = 0; j < 8; j++) {
      int pc = pc0 + j; int p = pr * 16 + pc;
      float a0 = 0.f, a1 = 0.f; unsigned uc = 0;
#pragma unroll
      for (int dr = 0; dr < 3; dr++)
#pragma unroll
        for (int dc = 0; dc < 3; dc++) {
          unsigned u = *(const unsigned*)&Hl[((pr + dr) * 18 + pc + dc) * 64 + 2 * cp];
          if (dr == 1 && dc == 1) uc = u;
          a0 = fmaf(lo2f(u), wg0[dr * 3 + dc], a0);
          a1 = fmaf(hi2f(u), wg1[dr * 3 + dc], a1);
        }
      *(unsigned*)&Xl[p * 392 + gc] = uc;
      *(unsigned*)&Xl[p * 392 + 192 + gc] =
          (unsigned)f2bf(a0) | ((unsigned)f2bf(a1) << 16);
    }
  }
  __syncthreads();
  const u16* wdb = wdg + (size_t)b * 192 * 384;
  f32x4 z = {0.f, 0.f, 0.f, 0.f};
  f32x4 acc[3][4];
#pragma unroll
  for (int i = 0; i < 3; i++)
#pragma unroll
    for (int j = 0; j < 4; j++) acc[i][j] = z;
#pragma unroll 2
  for (int ks = 0; ks < 12; ks++) {
    int k0 = ks * 32 + grp * 8;
    s16x8 b0 = *(s16x8*)&Xl[r * 392 + k0];
    s16x8 b1 = *(s16x8*)&Xl[(16 + r) * 392 + k0];
    s16x8 b2 = *(s16x8*)&Xl[(32 + r) * 392 + k0];
    s16x8 b3 = *(s16x8*)&Xl[(48 + r) * 392 + k0];
#pragma unroll
    for (int mt = 0; mt < 3; mt++) {
      s16x8 a = *(const s16x8*)&wdb[(size_t)(wv * 48 + mt * 16 + r) * 384 + k0];
      acc[mt][0] = MFMA_BF16(a, b0, acc[mt][0]);
      acc[mt][1] = MFMA_BF16(a, b1, acc[mt][1]);
      acc[mt][2] = MFMA_BF16(a, b2, acc[mt][2]);
      acc[mt][3] = MFMA_BF16(a, b3, acc[mt][3]);
    }
  }
#pragma unroll
  for (int mt = 0; mt < 3; mt++)
#pragma unroll
    for (int nt = 0; nt < 4; nt++) {
      size_t base = ((size_t)b * NC + wv * 48 + mt * 16 + grp * 4) * HW +
                    (h0 + nt) * NW + w0 + r;
#pragma unroll
      for (int i = 0; i < 4; i++) {
        size_t idx = base + (size_t)i * HW;
        x2[idx] = acc[mt][nt][i] + xres[mt][nt][i];
      }
    }
}

// ---------------------------------------------------------------------------
// FUSED: depthwise 3x3 + GELU gating + ffn_out GEMM + residual, per band.
// T14 async-stage: the 48 per-thread x2-residual loads (100 MB stream) are
// issued in the prologue and consumed in the epilogue.
// ---------------------------------------------------------------------------
__global__ __launch_bounds__(256, 2)
void k_gelu_ffn_band(const u16* __restrict__ ypre, const float* __restrict__ wdwf,
                     const u16* __restrict__ wfo, const float* __restrict__ x2,
                     float* __restrict__ out, int r0) {
  __shared__ u16 H1[6 * 18 * 64];
  __shared__ u16 H2[6 * 18 * 72];
  __shared__ u16 Yc[64 * 80];       // ypm chunk: 64 px x 64 j (stride 80 for banks)
  int t = threadIdx.x;
  int b = blockIdx.x >> 6; int r2 = blockIdx.x & 63;
  int h0l = (r2 >> 3) * 4, w0 = (r2 & 7) * 16;
  int cp = t & 31, psub = t >> 5;
  int pr = psub >> 1, pc0 = (psub & 1) * 8;
  int lane = t & 63, wv = t >> 6;
  int r = lane & 15, grp = lane >> 4;
  int jl = 2 * cp;
  // --- prologue: issue residual loads early
  float x2res[3][4][4];
#pragma unroll
  for (int mt = 0; mt < 3; mt++)
#pragma unroll
    for (int nt = 0; nt < 4; nt++) {
      size_t base = ((size_t)b * NC + wv * 48 + mt * 16 + grp * 4) * HW +
                    (r0 + h0l + nt) * NW + w0 + r;
#pragma unroll
      for (int i = 0; i < 4; i++) x2res[mt][nt][i] = x2[base + (size_t)i * HW];
    }
  const s16x8 z8 = {0, 0, 0, 0, 0, 0, 0, 0};
  f32x4 z = {0.f, 0.f, 0.f, 0.f};
  f32x4 acc[3][4];
#pragma unroll
  for (int i = 0; i < 3; i++)
#pragma unroll
    for (int j = 0; j < 4; j++) acc[i][j] = z;

  for (int jc = 0; jc < 8; jc++) {
    int j0 = jc * 64;
    int base2 = j0 + 504;
    __syncthreads();   // previous iter's MFMA reads of Yc / dwconv reads of H done
    for (int i = t; i < 864; i += 256) {
      int px = i >> 3, sg = i & 7;
      int hh = px / 18, ww = px % 18;
      int slot = h0l + hh;
      int gh = r0 - 1 + slot, gw = w0 - 1 + ww;
      s16x8 v = z8;
      if (gh >= 0 && gh < NH && gw >= 0 && gw < NW)
        v = *(const s16x8*)&ypre[((size_t)b * BPIX + slot * NW + gw) * NG2P + j0 + sg * 8];
      *(s16x8*)&H1[(hh * 18 + ww) * 64 + sg * 8] = v;
    }
    for (int i = t; i < 972; i += 256) {
      int px = i / 9, sg = i % 9;
      int hh = px / 18, ww = px % 18;
      int slot = h0l + hh;
      int gh = r0 - 1 + slot, gw = w0 - 1 + ww;
      s16x8 v = z8;
      if (gh >= 0 && gh < NH && gw >= 0 && gw < NW)
        v = *(const s16x8*)&ypre[((size_t)b * BPIX + slot * NW + gw) * NG2P + base2 + sg * 8];
      *(s16x8*)&H2[(hh * 18 + ww) * 72 + sg * 8] = v;
    }
    __syncthreads();
    int j = j0 + jl;
    bool v0 = (j < NHID), v1 = (j + 1 < NHID);
    float w1a[9], w1b[9], w2a[9], w2b[9];
#pragma unroll
    for (int q = 0; q < 9; q++) {
      w1a[q] = 0.f; w1b[q] = 0.f; w2a[q] = 0.f; w2b[q] = 0.f;
      if (v0) { w1a[q] = wdwf[j * 9 + q]; w2a[q] = wdwf[(j + NHID) * 9 + q]; }
      if (v1) { w1b[q] = wdwf[(j + 1) * 9 + q]; w2b[q] = wdwf[(j + 1 + NHID) * 9 + q]; }
    }
#pragma unroll
    for (int jj = 0; jj < 8; jj++) {
      int pc = pc0 + jj;
      float d1a = 0.f, d1b = 0.f, d2a = 0.f, d2b = 0.f;
#pragma unroll
      for (int dr = 0; dr < 3; dr++)
#pragma unroll
        for (int dc = 0; dc < 3; dc++) {
          int q = dr * 3 + dc;
          unsigned u1 = *(const unsigned*)&H1[((pr + dr) * 18 + pc + dc) * 64 + jl];
          unsigned u2 = *(const unsigned*)&H2[((pr + dr) * 18 + pc + dc) * 72 + jl + 6];
          d1a = fmaf(lo2f(u1), w1a[q], d1a); d1b = fmaf(hi2f(u1), w1b[q], d1b);
          d2a = fmaf(lo2f(u2), w2a[q], d2a); d2b = fmaf(hi2f(u2), w2b[q], d2b);
        }
      float ga = 0.5f * d1a * (1.f + erff(d1a * 0.70710678118654752f));
      float gb = 0.5f * d1b * (1.f + erff(d1b * 0.70710678118654752f));
      float ya = v0 ? ga * d2a : 0.f;
      float yb = v1 ? gb * d2b : 0.f;
      int lp = pr * 16 + pc;           // local px 0..63
      *(unsigned*)&Yc[lp * 80 + jl] = (unsigned)f2bf(ya) | ((unsigned)f2bf(yb) << 16);
    }
    __syncthreads();
#pragma unroll
    for (int ks = 0; ks < 2; ks++) {
      int k0 = ks * 32 + grp * 8;
      s16x8 b0 = *(s16x8*)&Yc[r * 80 + k0];
      s16x8 b1 = *(s16x8*)&Yc[(16 + r) * 80 + k0];
      s16x8 b2 = *(s16x8*)&Yc[(32 + r) * 80 + k0];
      s16x8 b3 = *(s16x8*)&Yc[(48 + r) * 80 + k0];
#pragma unroll
      for (int mt = 0; mt < 3; mt++) {
        s16x8 a = *(const s16x8*)&wfo[(size_t)(wv * 48 + mt * 16 + r) * NHIDP + j0 + k0];
        acc[mt][0] = MFMA_BF16(a, b0, acc[mt][0]);
        acc[mt][1] = MFMA_BF16(a, b1, acc[mt][1]);
        acc[mt][2] = MFMA_BF16(a, b2, acc[mt][2]);
        acc[mt][3] = MFMA_BF16(a, b3, acc[mt][3]);
      }
    }
  }
  // epilogue: out = acc + x2 (prefetched)
#pragma unroll
  for (int mt = 0; mt < 3; mt++)
#pragma unroll
    for (int nt = 0; nt < 4; nt++) {
      size_t base = ((size_t)b * NC + wv * 48 + mt * 16 + grp * 4) * HW +
                    (r0 + h0l + nt) * NW + w0 + r;
#pragma unroll
      for (int i = 0; i < 4; i++) {
        size_t idx = base + (size_t)i * HW;
        out[idx] = acc[mt][nt][i] + x2res[mt][nt][i];
      }
    }
}

// ---------------------------------------------------------------------------
extern "C" void kernel_launch(void* const* d_in, const int* in_sizes, int n_in,
                              void* d_out, int out_size, void* d_ws, size_t ws_size,
                              hipStream_t stream) {
  const float* x      = (const float*)d_in[0];
  const float* ce     = (const float*)d_in[1];
  const float* ln1w   = (const float*)d_in[2];
  const float* ln1b   = (const float*)d_in[3];
  const float* ln2w   = (const float*)d_in[4];
  const float* ln2b   = (const float*)d_in[5];
  const float* wqkv   = (const float*)d_in[6];
  const float* wqkvdw = (const float*)d_in[7];
  const float* wproj  = (const float*)d_in[8];
  const float* btemp  = (const float*)d_in[9];
  const float* taw1   = (const float*)d_in[10];
  const float* tab1   = (const float*)d_in[11];
  const float* taw2   = (const float*)d_in[12];
  const float* tab2   = (const float*)d_in[13];
  const float* vgw    = (const float*)d_in[14];
  const float* vgb    = (const float*)d_in[15];
  const float* wlocal = (const float*)d_in[16];
  const float* wffni  = (const float*)d_in[17];
  const float* wffndw = (const float*)d_in[18];
  const float* wffno  = (const float*)d_in[19];
  float* outp = (float*)d_out;
  char* ws = (char*)d_ws;

  // workspace layout (bytes), peak 224,602,240
  const size_t REQUIRED = 224602240ULL;
  if (ws_size < REQUIRED) {  // diagnosable failure mode instead of a fault
    hipMemsetAsync(d_out, 0, (size_t)out_size * 4, stream);
    return;
  }
  u16*   wq_bf   = (u16*)(ws + 0);            // 221184
  u16*   wfi_bf  = (u16*)(ws + 221184);       // 393216
  u16*   wfo_bf  = (u16*)(ws + 614400);       // 196608
  float* tempt   = (float*)(ws + 811008);     // 128
  float* vg      = (float*)(ws + 811136);     // 6144
  float* ssq     = (float*)(ws + 817280);     // 12288
  float* attn    = (float*)(ws + 829568);     // 294912
  u16*   wdg     = (u16*)(ws + 1124480);      // 1179648
  u16*   qkvband = (u16*)(ws + 2304128);      // 40108032 (8*4352*576*2)
  u16*   qkband  = (u16*)(ws + 42412160);     // 25165824 (8*384*4096*2)
  u16*   ypreband= (u16*)(ws + 2304128);      // 71303168 (8*4352*1024*2) reuses qkv+qk
  u16*   vpm     = (u16*)(ws + 73607296);     // 50331648 (8*16384*192*2)
  float* x2      = (float*)(ws + 123938944);  // 100663296

  hipMemsetAsync(ws + 817280, 0, 12288 + 294912, stream);  // ssq + attn_raw
  k_prep<<<512, 256, 0, stream>>>(wqkv, wffni, wffno, wq_bf, wfi_bf, wfo_bf);
  k_ctx<<<8, 256, 0, stream>>>(ce, taw1, tab1, taw2, tab2, vgw, vgb, btemp, tempt, vg);

  for (int band = 0; band < 4; band++) {
    int r0 = band * BROWS;
    int rs = (r0 > 0) ? r0 - 1 : 0;
    int re = (r0 + BROWS + 1 < NH) ? r0 + BROWS + 1 : NH;
    int nr = re - rs;
    int s0 = rs - (r0 - 1);
    k_ln_gemm_band<<<8 * nr * 2, 256, 0, stream>>>(x, ln1w, ln1b, wq_bf, qkvband, 9, rs, s0);
    k_dw_attn_band<<<9 * 8 * 64, 256, 0, stream>>>(qkvband, wqkvdw, qkband, vpm, ssq, r0);
    k_attn_band<<<32 * 4, 256, 0, stream>>>(qkband, attn);
  }
  k_softmax<<<32, 64, 0, stream>>>(attn, ssq, tempt, vg);
  k_wd<<<64, 256, 0, stream>>>(attn, wproj, wdg);
  k_proj<<<2048, 256, 0, stream>>>(vpm, wlocal, wdg, x, x2);

  for (int band = 0; band < 4; band++) {
    int r0 = band * BROWS;
    int rs = (r0 > 0) ? r0 - 1 : 0;
    int re = (r0 + BROWS + 1 < NH) ? r0 + BROWS + 1 : NH;
    int nr = re - rs;
    int s0 = rs - (r0 - 1);
    k_ln_gemm_band<<<8 * nr * 2, 256, 0, stream>>>(x2, ln2w, ln2b, wfi_bf, ypreband, 16, rs, s0);
    k_gelu_ffn_band<<<8 * 64, 256, 0, stream>>>(ypreband, wffndw, wfo_bf, x2, outp, r0);
  }
}

// Round 4
// 1113.757 us; speedup vs baseline: 1.1386x; 1.1386x over previous
//
#include <hip/hip_runtime.h>
#include <math.h>

#define NB 8
#define NC 192
#define NH 128
#define NW 128
#define HW 16384
#define NQ 576
#define NHID 510
#define NHIDP 512
#define NG2 1020
#define NG2P 1024

// band geometry: 4 bands x 32 rows, 1-row halo each side -> 34-slot buffers
#define BROWS 32
#define BSLOTS 34
#define BPIX (BSLOTS * NW)      // 4352 pixels per batch in band buffer
#define BIPIX (BROWS * NW)      // 4096 interior pixels per batch

typedef unsigned short u16;
typedef short s16x8 __attribute__((ext_vector_type(8)));
typedef float f32x4 __attribute__((ext_vector_type(4)));

#define MFMA_BF16(a, b, c) __builtin_amdgcn_mfma_f32_16x16x32_bf16((a), (b), (c), 0, 0, 0)

__device__ __forceinline__ u16 f2bf(float f) {
  union { float f; unsigned u; } v; v.f = f;
  unsigned r = v.u + 0x7fffu + ((v.u >> 16) & 1u);
  return (u16)(r >> 16);
}
__device__ __forceinline__ float bf2f(u16 h) {
  union { unsigned u; float f; } v; v.u = ((unsigned)h) << 16; return v.f;
}
__device__ __forceinline__ float lo2f(unsigned u) {
  union { unsigned u; float f; } v; v.u = u << 16; return v.f;
}
__device__ __forceinline__ float hi2f(unsigned u) {
  union { unsigned u; float f; } v; v.u = u & 0xffff0000u; return v.f;
}

// async global->LDS DMA, 16B per lane.  LDS dest must be wave-uniform base +
// lane*16 (all staging loops below have lds_byte == i*16, i = t + k*256).
// The compiler cannot sink this intrinsic across barriers (unlike plain
// loads, which it sank in R3 defeating the reg-prefetch attempt).
__device__ __forceinline__ void gll16(const void* g, void* l) {
  __builtin_amdgcn_global_load_lds(
      (const __attribute__((address_space(1))) void*)g,
      (__attribute__((address_space(3))) void*)l, 16, 0, 0);
}

// ---------------------------------------------------------------------------
// Weight prep: fp32 -> bf16 (ffn_in padded to 1024 rows, ffn_out to 512 cols)
// ---------------------------------------------------------------------------
__global__ void k_prep(const float* __restrict__ wq, const float* __restrict__ wfi,
                       const float* __restrict__ wfo,
                       u16* __restrict__ oq, u16* __restrict__ ofi, u16* __restrict__ ofo) {
  const int n1 = NQ * NC, n2 = NG2P * NC, n3 = NC * NHIDP;
  for (int i = blockIdx.x * blockDim.x + threadIdx.x; i < n1 + n2 + n3;
       i += gridDim.x * blockDim.x) {
    if (i < n1) {
      oq[i] = f2bf(wq[i]);
    } else if (i < n1 + n2) {
      int j = i - n1; int row = j / NC;
      u16 v = 0;
      if (row < NG2) v = f2bf(wfi[j]);
      ofi[j] = v;
    } else {
      int j = i - n1 - n2; int row = j >> 9, col = j & 511;
      u16 v = 0;
      if (col < NHID) v = f2bf(wfo[row * NHID + col]);
      ofo[j] = v;
    }
  }
}

// ---------------------------------------------------------------------------
// Context adapters: temp_total (b,4) and v_gate (b,192)
// ---------------------------------------------------------------------------
__global__ void k_ctx(const float* __restrict__ ce, const float* __restrict__ taw1,
                      const float* __restrict__ tab1, const float* __restrict__ taw2,
                      const float* __restrict__ tab2, const float* __restrict__ vgw,
                      const float* __restrict__ vgb, const float* __restrict__ btemp,
                      float* __restrict__ tempt, float* __restrict__ vg) {
  int b = blockIdx.x, t = threadIdx.x;
  __shared__ float sce[256];
  __shared__ float shid[48];
  sce[t] = ce[b * 256 + t];
  __syncthreads();
  if (t < 48) {
    float s = tab1[t];
    for (int j = 0; j < 256; j++) s = fmaf(taw1[t * 256 + j], sce[j], s);
    shid[t] = fmaxf(s, 0.f);
  }
  __syncthreads();
  if (t < 4) {
    float s = tab2[t];
    for (int j = 0; j < 48; j++) s = fmaf(taw2[t * 48 + j], shid[j], s);
    float sg = 1.f / (1.f + expf(-s));
    tempt[b * 4 + t] = btemp[t] * (sg * 2.f + 0.5f);
  }
  if (t < 192) {
    float s = vgb[t];
    for (int j = 0; j < 256; j++) s = fmaf(vgw[t * 256 + j], sce[j], s);
    vg[b * 192 + t] = 1.f / (1.f + expf(-s));
  }
}

// ---------------------------------------------------------------------------
// Banded fused per-pixel LayerNorm (192 ch) + 1x1-conv GEMM (bf16 MFMA).
// ---------------------------------------------------------------------------
__global__ __launch_bounds__(256, 2)
void k_ln_gemm_band(const float* __restrict__ in, const float* __restrict__ lnw,
                    const float* __restrict__ lnb, const u16* __restrict__ wbf,
                    u16* __restrict__ out, int nchunks, int row_start, int slot0) {
  __shared__ u16 Xn[64 * 200];
  __shared__ u16 Wc[64 * 200];
  __shared__ float red[512];
  __shared__ float stats[128];
  int t = threadIdx.x;
  int lane = t & 63, wv = t >> 6;
  int bpb = gridDim.x >> 3;                 // blocks per batch = nrows*2
  int b = blockIdx.x / bpb;
  int rb = blockIdx.x - b * bpb;
  int gpx0 = row_start * NW + rb * 64;      // global pixel base
  int opx0 = slot0 * NW + rb * 64;          // band-local pixel base
  const float* xp = in + (size_t)b * NC * HW + gpx0 + lane;
  float vals[48];
  float s = 0.f, s2 = 0.f;
#pragma unroll
  for (int j = 0; j < 48; j++) {
    float v = xp[(size_t)(wv * 48 + j) * HW];
    vals[j] = v; s += v; s2 = fmaf(v, v, s2);
  }
  red[wv * 64 + lane] = s;
  red[256 + wv * 64 + lane] = s2;
  __syncthreads();
  if (t < 64) {
    float m = 0.f, q = 0.f;
#pragma unroll
    for (int k = 0; k < 4; k++) { m += red[k * 64 + t]; q += red[256 + k * 64 + t]; }
    m *= (1.f / 192.f);
    float var = q * (1.f / 192.f) - m * m;
    stats[t] = m; stats[64 + t] = rsqrtf(var + 1e-5f);
  }
  __syncthreads();
  float mu = stats[lane], rs = stats[64 + lane];
#pragma unroll
  for (int j = 0; j < 48; j += 2) {
    int c = wv * 48 + j;
    float xa = (vals[j] - mu) * rs * lnw[c] + lnb[c];
    float xb = (vals[j + 1] - mu) * rs * lnw[c + 1] + lnb[c + 1];
    *(unsigned*)&Xn[lane * 200 + c] = (unsigned)f2bf(xa) | ((unsigned)f2bf(xb) << 16);
  }
  int r = lane & 15, grp = lane >> 4;
  int ostride = nchunks << 6;
  for (int nc = 0; nc < nchunks; nc++) {
    __syncthreads();
    for (int i = t; i < 1536; i += 256) {
      int row = i / 24, sg = i % 24;
      *(s16x8*)&Wc[row * 200 + sg * 8] =
          *(const s16x8*)&wbf[(size_t)(nc * 64 + row) * 192 + sg * 8];
    }
    __syncthreads();
    f32x4 z = {0.f, 0.f, 0.f, 0.f};
    f32x4 acc0 = z, acc1 = z, acc2 = z, acc3 = z;
#pragma unroll
    for (int ks = 0; ks < 6; ks++) {
      int k0 = ks * 32 + grp * 8;
      s16x8 a = *(s16x8*)&Xn[(wv * 16 + r) * 200 + k0];
      acc0 = MFMA_BF16(a, *(s16x8*)&Wc[r * 200 + k0], acc0);
      acc1 = MFMA_BF16(a, *(s16x8*)&Wc[(16 + r) * 200 + k0], acc1);
      acc2 = MFMA_BF16(a, *(s16x8*)&Wc[(32 + r) * 200 + k0], acc2);
      acc3 = MFMA_BF16(a, *(s16x8*)&Wc[(48 + r) * 200 + k0], acc3);
    }
    u16* op = out + ((size_t)b * BPIX + opx0 + wv * 16 + grp * 4) * ostride + nc * 64 + r;
#pragma unroll
    for (int i = 0; i < 4; i++) {
      op[(size_t)i * ostride] = f2bf(acc0[i]);
      op[(size_t)i * ostride + 16] = f2bf(acc1[i]);
      op[(size_t)i * ostride + 32] = f2bf(acc2[i]);
      op[(size_t)i * ostride + 48] = f2bf(acc3[i]);
    }
  }
}

// ---------------------------------------------------------------------------
// Banded depthwise 3x3 on qkv band buffer [B][BPIX][576] bf16.
// Halo staging via global_load_lds DMA (no VGPR round-trip); OOB lanes read
// a zero page through their per-lane global address.
// ---------------------------------------------------------------------------
__global__ __launch_bounds__(256, 4)
void k_dw_attn_band(const u16* __restrict__ qb_band, const float* __restrict__ wdw,
                    u16* __restrict__ qkb, u16* __restrict__ vpm,
                    float* __restrict__ ssq, int r0, const u16* __restrict__ zp) {
  __shared__ u16 Hl[6 * 18 * 64];
  __shared__ float sred[8 * 64];
  int t = threadIdx.x;
  int cc = blockIdx.x % 9;
  int rem = blockIdx.x / 9;        // 512 values
  int b = rem >> 6; int r2 = rem & 63;
  int h0l = (r2 >> 3) * 4, w0 = (r2 & 7) * 16;   // band-local interior row, col
  int c0 = cc * 64;
  const s16x8 z8 = {0, 0, 0, 0, 0, 0, 0, 0};
  for (int i = t; i < 864; i += 256) {
    int px = i >> 3, sg = i & 7;
    int hh = px / 18, ww = px % 18;
    int slot = h0l + hh;                 // in [0, 34)
    int gh = r0 - 1 + slot;
    int gw = w0 - 1 + ww;
    const void* g = (gh >= 0 && gh < NH && gw >= 0 && gw < NW)
        ? (const void*)&qb_band[((size_t)b * BPIX + slot * NW + gw) * NQ + c0 + sg * 8]
        : (const void*)zp;
    gll16(g, &Hl[i * 8]);
  }
  __syncthreads();
  int cp = t & 31, psub = t >> 5;
  int pr = psub >> 1, pc0 = (psub & 1) * 8;
  int gc = c0 + 2 * cp;
  float wg0[9], wg1[9];
#pragma unroll
  for (int q = 0; q < 9; q++) { wg0[q] = wdw[gc * 9 + q]; wg1[q] = wdw[(gc + 1) * 9 + q]; }
  bool isv = (c0 >= 384);
  float sq0 = 0.f, sq1 = 0.f;
  s16x8 ov0 = z8, ov1 = z8;
#pragma unroll
  for (int j = 0; j < 8; j++) {
    int pc = pc0 + j;
    float a0 = 0.f, a1 = 0.f;
#pragma unroll
    for (int dr = 0; dr < 3; dr++)
#pragma unroll
      for (int dc = 0; dc < 3; dc++) {
        unsigned u = *(const unsigned*)&Hl[((pr + dr) * 18 + pc + dc) * 64 + 2 * cp];
        a0 = fmaf(lo2f(u), wg0[dr * 3 + dc], a0);
        a1 = fmaf(hi2f(u), wg1[dr * 3 + dc], a1);
      }
    u16 u0 = f2bf(a0), u1 = f2bf(a1);
    if (isv) {
      int gp = (r0 + h0l + pr) * NW + w0 + pc;   // global pixel
      *(unsigned*)&vpm[((size_t)b * HW + gp) * 192 + (gc - 384)] =
          (unsigned)u0 | ((unsigned)u1 << 16);
    } else {
      ov0[j] = (short)u0; ov1[j] = (short)u1;
      float f0 = bf2f(u0), f1 = bf2f(u1);
      sq0 = fmaf(f0, f0, sq0); sq1 = fmaf(f1, f1, sq1);
    }
  }
  if (!isv) {
    int lpx = (h0l + pr) * NW + w0 + pc0;        // band-local pixel
    *(s16x8*)&qkb[((size_t)b * 384 + gc) * BIPIX + lpx] = ov0;
    *(s16x8*)&qkb[((size_t)b * 384 + gc + 1) * BIPIX + lpx] = ov1;
    sred[psub * 64 + 2 * cp] = sq0;
    sred[psub * 64 + 2 * cp + 1] = sq1;
    __syncthreads();
    if (t < 64) {
      float sa = 0.f;
#pragma unroll
      for (int p8 = 0; p8 < 8; p8++) sa += sred[p8 * 64 + t];
      atomicAdd(&ssq[b * 384 + c0 + t], sa);
    }
  }
}

// ---------------------------------------------------------------------------
// attn_raw[b,h,c,d] += sum_{band px} q[c,px]*k[d,px]  (MFMA, K split 4 ways)
// ---------------------------------------------------------------------------
__global__ __launch_bounds__(256, 2)
void k_attn_band(const u16* __restrict__ qkb, float* __restrict__ attn) {
  __shared__ float par[4 * 2304];
  int t = threadIdx.x;
  int lane = t & 63, wv = t >> 6;
  int r = lane & 15, grp = lane >> 4;
  int bh = blockIdx.x >> 2, kc = blockIdx.x & 3;
  int b = bh >> 2, h = bh & 3;
  const u16* qb = qkb + ((size_t)b * 384 + h * 48) * BIPIX;
  const u16* kb = qkb + ((size_t)b * 384 + 192 + h * 48) * BIPIX;
  f32x4 z = {0.f, 0.f, 0.f, 0.f};
  f32x4 acc[3][3];
#pragma unroll
  for (int i = 0; i < 3; i++)
#pragma unroll
    for (int j = 0; j < 3; j++) acc[i][j] = z;
  int kbase = kc * 1024 + wv * 256 + grp * 8;
#pragma unroll 2
  for (int ks = 0; ks < 8; ks++) {
    int k0 = kbase + ks * 32;
    s16x8 af[3], bf[3];
#pragma unroll
    for (int mt = 0; mt < 3; mt++) af[mt] = *(const s16x8*)&qb[(size_t)(mt * 16 + r) * BIPIX + k0];
#pragma unroll
    for (int nt = 0; nt < 3; nt++) bf[nt] = *(const s16x8*)&kb[(size_t)(nt * 16 + r) * BIPIX + k0];
#pragma unroll
    for (int mt = 0; mt < 3; mt++)
#pragma unroll
      for (int nt = 0; nt < 3; nt++) acc[mt][nt] = MFMA_BF16(af[mt], bf[nt], acc[mt][nt]);
  }
#pragma unroll
  for (int mt = 0; mt < 3; mt++)
#pragma unroll
    for (int nt = 0; nt < 3; nt++)
#pragma unroll
      for (int i = 0; i < 4; i++)
        par[wv * 2304 + (mt * 16 + grp * 4 + i) * 48 + nt * 16 + r] = acc[mt][nt][i];
  __syncthreads();
  float* ag = attn + (size_t)bh * 2304;
  for (int i = t; i < 2304; i += 256)
    atomicAdd(&ag[i], par[i] + par[2304 + i] + par[4608 + i] + par[6912 + i]);
}

// ---------------------------------------------------------------------------
// Softmax over d with q/k norms, scale, temp; fold v_gate in (in place)
// ---------------------------------------------------------------------------
__global__ void k_softmax(float* __restrict__ attn, const float* __restrict__ ssq,
                          const float* __restrict__ tempt, const float* __restrict__ vg) {
  int bh = blockIdx.x, b = bh >> 2, h = bh & 3;
  int t = threadIdx.x;  // 64
  __shared__ float srk[48], svg[48];
  if (t < 48) {
    float nk = sqrtf(ssq[b * 384 + 192 + h * 48 + t]);
    srk[t] = 1.f / fmaxf(nk, 1e-12f);
    svg[t] = vg[b * 192 + h * 48 + t];
  }
  __syncthreads();
  if (t < 48) {
    float nq = sqrtf(ssq[b * 384 + h * 48 + t]);
    float rq = 1.f / fmaxf(nq, 1e-12f);
    float sc = 0.14433756729740643f * tempt[b * 4 + h] * rq;
    float* row = attn + (size_t)bh * 2304 + t * 48;
    float l[48]; float mx = -1e30f;
#pragma unroll
    for (int d = 0; d < 48; d++) { l[d] = row[d] * srk[d] * sc; mx = fmaxf(mx, l[d]); }
    float ss = 0.f;
#pragma unroll
    for (int d = 0; d < 48; d++) { l[d] = expf(l[d] - mx); ss += l[d]; }
    float inv = 1.f / ss;
#pragma unroll
    for (int d = 0; d < 48; d++) row[d] = l[d] * inv * svg[d];
  }
}

// ---------------------------------------------------------------------------
// W_D[b] = [ w_proj @ blockdiag(attn') | w_proj ]  (192 x 384 bf16 per batch)
// ---------------------------------------------------------------------------
__global__ __launch_bounds__(256)
void k_wd(const float* __restrict__ attn, const float* __restrict__ wp,
          u16* __restrict__ wdg) {
  __shared__ float am[4 * 48 * 48];
  int b = blockIdx.x >> 3, oc = blockIdx.x & 7;
  int t = threadIdx.x;
  const float* ag = attn + (size_t)b * 4 * 2304;
  for (int i = t; i < 9216; i += 256) am[i] = ag[i];
  __syncthreads();
  u16* wdb = wdg + (size_t)b * 192 * 384;
  for (int idx = t; idx < 24 * 384; idx += 256) {
    int oo = idx / 384, j = idx % 384;
    int o = oc * 24 + oo;
    float val;
    if (j < 192) {
      int hj = j / 48, dj = j % 48;
      const float* wpo = wp + o * 192 + hj * 48;
      const float* ap = am + hj * 2304 + dj;
      float sa = 0.f;
#pragma unroll
      for (int c = 0; c < 48; c++) sa = fmaf(wpo[c], ap[c * 48], sa);
      val = sa;
    } else {
      val = wp[o * 192 + (j - 192)];
    }
    wdb[o * 384 + j] = f2bf(val);
  }
}

// ---------------------------------------------------------------------------
// x2 = x + W_D @ [v ; dwconv3x3_local(v)] per 4x16 pixel tile (MFMA, K=384)
// Double-buffered halo staging via global_load_lds DMA: chunk c3+1's halo is
// issued BEFORE chunk c3's dwconv, so the DMA flies under the VALU phase and
// the compiler's vmcnt(0)-at-barrier drain lands after the work, not before.
// ---------------------------------------------------------------------------
__global__ __launch_bounds__(256, 2)
void k_proj(const u16* __restrict__ vpm, const float* __restrict__ wl,
            const u16* __restrict__ wdg, const float* __restrict__ x,
            float* __restrict__ x2, const u16* __restrict__ zp) {
  __shared__ u16 Hl[2][6 * 18 * 64];
  __shared__ u16 Xl[64 * 392];
  int t = threadIdx.x;
  int b = blockIdx.x >> 8; int r2 = blockIdx.x & 255;
  int h0 = (r2 >> 3) * 4, w0 = (r2 & 7) * 16;
  int cp = t & 31, psub = t >> 5;
  int pr = psub >> 1, pc0 = (psub & 1) * 8;
  int lane = t & 63, wv = t >> 6;
  int r = lane & 15, grp = lane >> 4;
  // residual prefetch (issue-early; harmless if compiler sinks it)
  float xres[3][4][4];
#pragma unroll
  for (int mt = 0; mt < 3; mt++)
#pragma unroll
    for (int nt = 0; nt < 4; nt++) {
      size_t base = ((size_t)b * NC + wv * 48 + mt * 16 + grp * 4) * HW +
                    (h0 + nt) * NW + w0 + r;
#pragma unroll
      for (int i = 0; i < 4; i++) xres[mt][nt][i] = x[base + (size_t)i * HW];
    }

  auto stageH = [&](int c3s, int buf) {
    int c0s = c3s * 64;
    for (int i = t; i < 864; i += 256) {
      int px = i >> 3, sg = i & 7;
      int hh = px / 18, ww = px % 18;
      int gh = h0 - 1 + hh, gw = w0 - 1 + ww;
      const void* g = (gh >= 0 && gh < NH && gw >= 0 && gw < NW)
          ? (const void*)&vpm[((size_t)b * HW + gh * NW + gw) * 192 + c0s + sg * 8]
          : (const void*)zp;
      gll16(g, &Hl[buf][i * 8]);
    }
  };

  stageH(0, 0);
  __syncthreads();           // drains DMA: Hl[0] ready
  int cur = 0;
  for (int c3 = 0; c3 < 3; c3++) {
    if (c3 < 2) stageH(c3 + 1, cur ^ 1);   // DMA overlaps dwconv below
    int c0 = c3 * 64;
    int gc = c0 + 2 * cp;
    float wg0[9], wg1[9];
#pragma unroll
    for (int q = 0; q < 9; q++) { wg0[q] = wl[gc * 9 + q]; wg1[q] = wl[(gc + 1) * 9 + q]; }
#pragma unroll
    for (int j = 0; j < 8; j++) {
      int pc = pc0 + j; int p = pr * 16 + pc;
      float a0 = 0.f, a1 = 0.f; unsigned uc = 0;
#pragma unroll
      for (int dr = 0; dr < 3; dr++)
#pragma unroll
        for (int dc = 0; dc < 3; dc++) {
          unsigned u = *(const unsigned*)&Hl[cur][((pr + dr) * 18 + pc + dc) * 64 + 2 * cp];
          if (dr == 1 && dc == 1) uc = u;
          a0 = fmaf(lo2f(u), wg0[dr * 3 + dc], a0);
          a1 = fmaf(hi2f(u), wg1[dr * 3 + dc], a1);
        }
      *(unsigned*)&Xl[p * 392 + gc] = uc;
      *(unsigned*)&Xl[p * 392 + 192 + gc] =
          (unsigned)f2bf(a0) | ((unsigned)f2bf(a1) << 16);
    }
    __syncthreads();  // all reads of Hl[cur] done; DMA into Hl[cur^1] drained
    cur ^= 1;
  }
  const u16* wdb = wdg + (size_t)b * 192 * 384;
  f32x4 z = {0.f, 0.f, 0.f, 0.f};
  f32x4 acc[3][4];
#pragma unroll
  for (int i = 0; i < 3; i++)
#pragma unroll
    for (int j = 0; j < 4; j++) acc[i][j] = z;
#pragma unroll 2
  for (int ks = 0; ks < 12; ks++) {
    int k0 = ks * 32 + grp * 8;
    s16x8 b0 = *(s16x8*)&Xl[r * 392 + k0];
    s16x8 b1 = *(s16x8*)&Xl[(16 + r) * 392 + k0];
    s16x8 b2 = *(s16x8*)&Xl[(32 + r) * 392 + k0];
    s16x8 b3 = *(s16x8*)&Xl[(48 + r) * 392 + k0];
#pragma unroll
    for (int mt = 0; mt < 3; mt++) {
      s16x8 a = *(const s16x8*)&wdb[(size_t)(wv * 48 + mt * 16 + r) * 384 + k0];
      acc[mt][0] = MFMA_BF16(a, b0, acc[mt][0]);
      acc[mt][1] = MFMA_BF16(a, b1, acc[mt][1]);
      acc[mt][2] = MFMA_BF16(a, b2, acc[mt][2]);
      acc[mt][3] = MFMA_BF16(a, b3, acc[mt][3]);
    }
  }
#pragma unroll
  for (int mt = 0; mt < 3; mt++)
#pragma unroll
    for (int nt = 0; nt < 4; nt++) {
      size_t base = ((size_t)b * NC + wv * 48 + mt * 16 + grp * 4) * HW +
                    (h0 + nt) * NW + w0 + r;
#pragma unroll
      for (int i = 0; i < 4; i++) {
        size_t idx = base + (size_t)i * HW;
        x2[idx] = acc[mt][nt][i] + xres[mt][nt][i];
      }
    }
}

// ---------------------------------------------------------------------------
// FUSED: depthwise 3x3 + GELU gating + ffn_out GEMM + residual, per band.
// Double-buffered H1/H2 halo staging via global_load_lds DMA: chunk jc+1's
// halo is issued before jc's dwconv+gelu (the erf-heavy long phase), so the
// DMA latency hides under it.  x2 residual loaded at use (R3's prologue
// variant regressed ~60us from register pressure - reverted).
// ---------------------------------------------------------------------------
__global__ __launch_bounds__(256, 2)
void k_gelu_ffn_band(const u16* __restrict__ ypre, const float* __restrict__ wdwf,
                     const u16* __restrict__ wfo, const float* __restrict__ x2,
                     float* __restrict__ out, int r0, const u16* __restrict__ zp) {
  __shared__ u16 H1[2][6 * 18 * 64];
  __shared__ u16 H2[2][6 * 18 * 72];
  __shared__ u16 Yc[64 * 80];       // ypm chunk: 64 px x 64 j (stride 80 for banks)
  int t = threadIdx.x;
  int b = blockIdx.x >> 6; int r2 = blockIdx.x & 63;
  int h0l = (r2 >> 3) * 4, w0 = (r2 & 7) * 16;
  int cp = t & 31, psub = t >> 5;
  int pr = psub >> 1, pc0 = (psub & 1) * 8;
  int lane = t & 63, wv = t >> 6;
  int r = lane & 15, grp = lane >> 4;
  int jl = 2 * cp;

  auto stage = [&](int jc, int buf) {
    int j0s = jc * 64;
    int base2 = j0s + 504;
    for (int i = t; i < 864; i += 256) {
      int px = i >> 3, sg = i & 7;
      int hh = px / 18, ww = px % 18;
      int slot = h0l + hh;
      int gh = r0 - 1 + slot, gw = w0 - 1 + ww;
      const void* g = (gh >= 0 && gh < NH && gw >= 0 && gw < NW)
          ? (const void*)&ypre[((size_t)b * BPIX + slot * NW + gw) * NG2P + j0s + sg * 8]
          : (const void*)zp;
      gll16(g, &H1[buf][i * 8]);
    }
    for (int i = t; i < 972; i += 256) {
      int px = i / 9, sg = i - px * 9;
      int hh = px / 18, ww = px % 18;
      int slot = h0l + hh;
      int gh = r0 - 1 + slot, gw = w0 - 1 + ww;
      const void* g = (gh >= 0 && gh < NH && gw >= 0 && gw < NW)
          ? (const void*)&ypre[((size_t)b * BPIX + slot * NW + gw) * NG2P + base2 + sg * 8]
          : (const void*)zp;
      gll16(g, &H2[buf][i * 8]);
    }
  };

  f32x4 z = {0.f, 0.f, 0.f, 0.f};
  f32x4 acc[3][4];
#pragma unroll
  for (int i = 0; i < 3; i++)
#pragma unroll
    for (int j = 0; j < 4; j++) acc[i][j] = z;

  stage(0, 0);
  __syncthreads();           // H[0] ready
  int cur = 0;
  for (int jc = 0; jc < 8; jc++) {
    if (jc < 7) stage(jc + 1, cur ^ 1);   // DMA overlaps dwconv+gelu below
    int j0 = jc * 64;
    int j = j0 + jl;
    bool v0 = (j < NHID), v1 = (j + 1 < NHID);
    float w1a[9], w1b[9], w2a[9], w2b[9];
#pragma unroll
    for (int q = 0; q < 9; q++) {
      w1a[q] = 0.f; w1b[q] = 0.f; w2a[q] = 0.f; w2b[q] = 0.f;
      if (v0) { w1a[q] = wdwf[j * 9 + q]; w2a[q] = wdwf[(j + NHID) * 9 + q]; }
      if (v1) { w1b[q] = wdwf[(j + 1) * 9 + q]; w2b[q] = wdwf[(j + 1 + NHID) * 9 + q]; }
    }
#pragma unroll
    for (int jj = 0; jj < 8; jj++) {
      int pc = pc0 + jj;
      float d1a = 0.f, d1b = 0.f, d2a = 0.f, d2b = 0.f;
#pragma unroll
      for (int dr = 0; dr < 3; dr++)
#pragma unroll
        for (int dc = 0; dc < 3; dc++) {
          int q = dr * 3 + dc;
          unsigned u1 = *(const unsigned*)&H1[cur][((pr + dr) * 18 + pc + dc) * 64 + jl];
          unsigned u2 = *(const unsigned*)&H2[cur][((pr + dr) * 18 + pc + dc) * 72 + jl + 6];
          d1a = fmaf(lo2f(u1), w1a[q], d1a); d1b = fmaf(hi2f(u1), w1b[q], d1b);
          d2a = fmaf(lo2f(u2), w2a[q], d2a); d2b = fmaf(hi2f(u2), w2b[q], d2b);
        }
      float ga = 0.5f * d1a * (1.f + erff(d1a * 0.70710678118654752f));
      float gb = 0.5f * d1b * (1.f + erff(d1b * 0.70710678118654752f));
      float ya = v0 ? ga * d2a : 0.f;
      float yb = v1 ? gb * d2b : 0.f;
      int lp = pr * 16 + pc;           // local px 0..63
      *(unsigned*)&Yc[lp * 80 + jl] = (unsigned)f2bf(ya) | ((unsigned)f2bf(yb) << 16);
    }
    __syncthreads();   // Yc ready; DMA for cur^1 drained here too
#pragma unroll
    for (int ks = 0; ks < 2; ks++) {
      int k0 = ks * 32 + grp * 8;
      s16x8 b0 = *(s16x8*)&Yc[r * 80 + k0];
      s16x8 b1 = *(s16x8*)&Yc[(16 + r) * 80 + k0];
      s16x8 b2 = *(s16x8*)&Yc[(32 + r) * 80 + k0];
      s16x8 b3 = *(s16x8*)&Yc[(48 + r) * 80 + k0];
#pragma unroll
      for (int mt = 0; mt < 3; mt++) {
        s16x8 a = *(const s16x8*)&wfo[(size_t)(wv * 48 + mt * 16 + r) * NHIDP + j0 + k0];
        acc[mt][0] = MFMA_BF16(a, b0, acc[mt][0]);
        acc[mt][1] = MFMA_BF16(a, b1, acc[mt][1]);
        acc[mt][2] = MFMA_BF16(a, b2, acc[mt][2]);
        acc[mt][3] = MFMA_BF16(a, b3, acc[mt][3]);
      }
    }
    __syncthreads();   // Yc consumed; safe to overwrite next iter
    cur ^= 1;
  }
  // epilogue: out = acc + x2
#pragma unroll
  for (int mt = 0; mt < 3; mt++)
#pragma unroll
    for (int nt = 0; nt < 4; nt++) {
      size_t base = ((size_t)b * NC + wv * 48 + mt * 16 + grp * 4) * HW +
                    (r0 + h0l + nt) * NW + w0 + r;
#pragma unroll
      for (int i = 0; i < 4; i++) {
        size_t idx = base + (size_t)i * HW;
        out[idx] = acc[mt][nt][i] + x2[idx];
      }
    }
}

// ---------------------------------------------------------------------------
extern "C" void kernel_launch(void* const* d_in, const int* in_sizes, int n_in,
                              void* d_out, int out_size, void* d_ws, size_t ws_size,
                              hipStream_t stream) {
  const float* x      = (const float*)d_in[0];
  const float* ce     = (const float*)d_in[1];
  const float* ln1w   = (const float*)d_in[2];
  const float* ln1b   = (const float*)d_in[3];
  const float* ln2w   = (const float*)d_in[4];
  const float* ln2b   = (const float*)d_in[5];
  const float* wqkv   = (const float*)d_in[6];
  const float* wqkvdw = (const float*)d_in[7];
  const float* wproj  = (const float*)d_in[8];
  const float* btemp  = (const float*)d_in[9];
  const float* taw1   = (const float*)d_in[10];
  const float* tab1   = (const float*)d_in[11];
  const float* taw2   = (const float*)d_in[12];
  const float* tab2   = (const float*)d_in[13];
  const float* vgw    = (const float*)d_in[14];
  const float* vgb    = (const float*)d_in[15];
  const float* wlocal = (const float*)d_in[16];
  const float* wffni  = (const float*)d_in[17];
  const float* wffndw = (const float*)d_in[18];
  const float* wffno  = (const float*)d_in[19];
  float* outp = (float*)d_out;
  char* ws = (char*)d_ws;

  // workspace layout (bytes), peak 224,602,240 + 256 zero page
  const size_t REQUIRED = 224602496ULL;
  if (ws_size < REQUIRED) {  // diagnosable failure mode instead of a fault
    hipMemsetAsync(d_out, 0, (size_t)out_size * 4, stream);
    return;
  }
  u16*   wq_bf   = (u16*)(ws + 0);            // 221184
  u16*   wfi_bf  = (u16*)(ws + 221184);       // 393216
  u16*   wfo_bf  = (u16*)(ws + 614400);       // 196608
  float* tempt   = (float*)(ws + 811008);     // 128
  float* vg      = (float*)(ws + 811136);     // 6144
  float* ssq     = (float*)(ws + 817280);     // 12288
  float* attn    = (float*)(ws + 829568);     // 294912
  u16*   wdg     = (u16*)(ws + 1124480);      // 1179648
  u16*   qkvband = (u16*)(ws + 2304128);      // 40108032 (8*4352*576*2)
  u16*   qkband  = (u16*)(ws + 42412160);     // 25165824 (8*384*4096*2)
  u16*   ypreband= (u16*)(ws + 2304128);      // 71303168 (8*4352*1024*2) reuses qkv+qk
  u16*   vpm     = (u16*)(ws + 73607296);     // 50331648 (8*16384*192*2)
  float* x2      = (float*)(ws + 123938944);  // 100663296
  u16*   zp      = (u16*)(ws + 224602240);    // 256 zero page for OOB DMA lanes

  hipMemsetAsync(ws + 817280, 0, 12288 + 294912, stream);  // ssq + attn_raw
  hipMemsetAsync(ws + 224602240, 0, 256, stream);          // zero page
  k_prep<<<512, 256, 0, stream>>>(wqkv, wffni, wffno, wq_bf, wfi_bf, wfo_bf);
  k_ctx<<<8, 256, 0, stream>>>(ce, taw1, tab1, taw2, tab2, vgw, vgb, btemp, tempt, vg);

  for (int band = 0; band < 4; band++) {
    int r0 = band * BROWS;
    int rs = (r0 > 0) ? r0 - 1 : 0;
    int re = (r0 + BROWS + 1 < NH) ? r0 + BROWS + 1 : NH;
    int nr = re - rs;
    int s0 = rs - (r0 - 1);
    k_ln_gemm_band<<<8 * nr * 2, 256, 0, stream>>>(x, ln1w, ln1b, wq_bf, qkvband, 9, rs, s0);
    k_dw_attn_band<<<9 * 8 * 64, 256, 0, stream>>>(qkvband, wqkvdw, qkband, vpm, ssq, r0, zp);
    k_attn_band<<<32 * 4, 256, 0, stream>>>(qkband, attn);
  }
  k_softmax<<<32, 64, 0, stream>>>(attn, ssq, tempt, vg);
  k_wd<<<64, 256, 0, stream>>>(attn, wproj, wdg);
  k_proj<<<2048, 256, 0, stream>>>(vpm, wlocal, wdg, x, x2, zp);

  for (int band = 0; band < 4; band++) {
    int r0 = band * BROWS;
    int rs = (r0 > 0) ? r0 - 1 : 0;
    int re = (r0 + BROWS + 1 < NH) ? r0 + BROWS + 1 : NH;
    int nr = re - rs;
    int s0 = rs - (r0 - 1);
    k_ln_gemm_band<<<8 * nr * 2, 256, 0, stream>>>(x2, ln2w, ln2b, wfi_bf, ypreband, 16, rs, s0);
    k_gelu_ffn_band<<<8 * 64, 256, 0, stream>>>(ypreband, wffndw, wfo_bf, x2, outp, r0, zp);
  }
}

// Round 5
// 1075.820 us; speedup vs baseline: 1.1788x; 1.0353x over previous
//
#include <hip/hip_runtime.h>
#include <math.h>

#define NB 8
#define NC 192
#define NH 128
#define NW 128
#define HW 16384
#define NQ 576
#define NHID 510
#define NHIDP 512
#define NG2 1020
#define NG2P 1024

// band geometry: 4 bands x 32 rows, 1-row halo each side -> 34-slot buffers
#define BROWS 32
#define BSLOTS 34
#define BPIX (BSLOTS * NW)      // 4352 pixels per batch in band buffer
#define BIPIX (BROWS * NW)      // 4096 interior pixels per batch

typedef unsigned short u16;
typedef short s16x8 __attribute__((ext_vector_type(8)));
typedef float f32x4 __attribute__((ext_vector_type(4)));

#define MFMA_BF16(a, b, c) __builtin_amdgcn_mfma_f32_16x16x32_bf16((a), (b), (c), 0, 0, 0)

__device__ __forceinline__ u16 f2bf(float f) {
  union { float f; unsigned u; } v; v.f = f;
  unsigned r = v.u + 0x7fffu + ((v.u >> 16) & 1u);
  return (u16)(r >> 16);
}
__device__ __forceinline__ float bf2f(u16 h) {
  union { unsigned u; float f; } v; v.u = ((unsigned)h) << 16; return v.f;
}
__device__ __forceinline__ float lo2f(unsigned u) {
  union { unsigned u; float f; } v; v.u = u << 16; return v.f;
}
__device__ __forceinline__ float hi2f(unsigned u) {
  union { unsigned u; float f; } v; v.u = u & 0xffff0000u; return v.f;
}

// async global->LDS DMA, 16B per lane.  LDS dest must be wave-uniform base +
// lane*16.  The compiler cannot sink this intrinsic across barriers.
__device__ __forceinline__ void gll16(const void* g, void* l) {
  __builtin_amdgcn_global_load_lds(
      (const __attribute__((address_space(1))) void*)g,
      (__attribute__((address_space(3))) void*)l, 16, 0, 0);
}

// ---------------------------------------------------------------------------
// Weight prep: fp32 -> bf16.  wq/wfi are stored GRANULE-SWIZZLED (16B granule
// g of row stored at position g ^ (row&7)) so k_ln_gemm_band can DMA them
// linearly into an unpadded [64][192] LDS tile and read conflict-free with
// the same XOR on the read side (rule: inverse-swz source + swz read).
// ffn_in padded to 1024 rows, ffn_out to 512 cols (wfo stays linear).
// ---------------------------------------------------------------------------
__global__ void k_prep(const float* __restrict__ wq, const float* __restrict__ wfi,
                       const float* __restrict__ wfo,
                       u16* __restrict__ oq, u16* __restrict__ ofi, u16* __restrict__ ofo) {
  const int n1 = NQ * NC, n2 = NG2P * NC, n3 = NC * NHIDP;
  for (int i = blockIdx.x * blockDim.x + threadIdx.x; i < n1 + n2 + n3;
       i += gridDim.x * blockDim.x) {
    if (i < n1) {
      int row = i / NC, col = i - row * NC;
      int g = col >> 3, o = col & 7;
      int sc = (((g ^ (row & 7)) << 3) | o);
      oq[i] = f2bf(wq[row * NC + sc]);
    } else if (i < n1 + n2) {
      int j = i - n1; int row = j / NC, col = j - row * NC;
      int g = col >> 3, o = col & 7;
      int sc = (((g ^ (row & 7)) << 3) | o);
      u16 v = 0;
      if (row < NG2) v = f2bf(wfi[row * NC + sc]);
      ofi[j] = v;
    } else {
      int j = i - n1 - n2; int row = j >> 9, col = j & 511;
      u16 v = 0;
      if (col < NHID) v = f2bf(wfo[row * NHID + col]);
      ofo[j] = v;
    }
  }
}

// ---------------------------------------------------------------------------
// Context adapters: temp_total (b,4) and v_gate (b,192)
// ---------------------------------------------------------------------------
__global__ void k_ctx(const float* __restrict__ ce, const float* __restrict__ taw1,
                      const float* __restrict__ tab1, const float* __restrict__ taw2,
                      const float* __restrict__ tab2, const float* __restrict__ vgw,
                      const float* __restrict__ vgb, const float* __restrict__ btemp,
                      float* __restrict__ tempt, float* __restrict__ vg) {
  int b = blockIdx.x, t = threadIdx.x;
  __shared__ float sce[256];
  __shared__ float shid[48];
  sce[t] = ce[b * 256 + t];
  __syncthreads();
  if (t < 48) {
    float s = tab1[t];
    for (int j = 0; j < 256; j++) s = fmaf(taw1[t * 256 + j], sce[j], s);
    shid[t] = fmaxf(s, 0.f);
  }
  __syncthreads();
  if (t < 4) {
    float s = tab2[t];
    for (int j = 0; j < 48; j++) s = fmaf(taw2[t * 48 + j], shid[j], s);
    float sg = 1.f / (1.f + expf(-s));
    tempt[b * 4 + t] = btemp[t] * (sg * 2.f + 0.5f);
  }
  if (t < 192) {
    float s = vgb[t];
    for (int j = 0; j < 256; j++) s = fmaf(vgw[t * 256 + j], sce[j], s);
    vg[b * 192 + t] = 1.f / (1.f + expf(-s));
  }
}

// ---------------------------------------------------------------------------
// Banded fused per-pixel LayerNorm (192 ch) + 1x1-conv GEMM (bf16 MFMA).
// Weight chunks now DMA'd (double-buffered) into unpadded [64][192] LDS from
// the pre-swizzled global copy; MFMA B-reads apply the matching granule XOR
// (bank-conflict-free: rows spaced 384B land on bank 0, XOR spreads the 16
// lanes of a b128 read across 8 bank-groups -> 2-way, free).
// One barrier per chunk (was two); DMA for chunk nc+1 flies under MFMA of nc.
// ---------------------------------------------------------------------------
__global__ __launch_bounds__(256, 2)
void k_ln_gemm_band(const float* __restrict__ in, const float* __restrict__ lnw,
                    const float* __restrict__ lnb, const u16* __restrict__ wbf,
                    u16* __restrict__ out, int nchunks, int row_start, int slot0) {
  __shared__ u16 Xn[64 * 200];
  __shared__ u16 Wc[2][64 * 192];
  __shared__ float red[512];
  __shared__ float stats[128];
  int t = threadIdx.x;
  int lane = t & 63, wv = t >> 6;
  int bpb = gridDim.x >> 3;                 // blocks per batch = nrows*2
  int b = blockIdx.x / bpb;
  int rb = blockIdx.x - b * bpb;
  int gpx0 = row_start * NW + rb * 64;      // global pixel base
  int opx0 = slot0 * NW + rb * 64;          // band-local pixel base
  const float* xp = in + (size_t)b * NC * HW + gpx0 + lane;
  float vals[48];
  float s = 0.f, s2 = 0.f;
#pragma unroll
  for (int j = 0; j < 48; j++) {
    float v = xp[(size_t)(wv * 48 + j) * HW];
    vals[j] = v; s += v; s2 = fmaf(v, v, s2);
  }
  red[wv * 64 + lane] = s;
  red[256 + wv * 64 + lane] = s2;
  __syncthreads();
  if (t < 64) {
    float m = 0.f, q = 0.f;
#pragma unroll
    for (int k = 0; k < 4; k++) { m += red[k * 64 + t]; q += red[256 + k * 64 + t]; }
    m *= (1.f / 192.f);
    float var = q * (1.f / 192.f) - m * m;
    stats[t] = m; stats[64 + t] = rsqrtf(var + 1e-5f);
  }
  __syncthreads();
  float mu = stats[lane], rs = stats[64 + lane];
#pragma unroll
  for (int j = 0; j < 48; j += 2) {
    int c = wv * 48 + j;
    float xa = (vals[j] - mu) * rs * lnw[c] + lnb[c];
    float xb = (vals[j + 1] - mu) * rs * lnw[c + 1] + lnb[c + 1];
    *(unsigned*)&Xn[lane * 200 + c] = (unsigned)f2bf(xa) | ((unsigned)f2bf(xb) << 16);
  }
  int r = lane & 15, grp = lane >> 4;
  int key = r & 7;
  int ostride = nchunks << 6;

  auto stageW = [&](int nc, int buf) {
    const u16* src = wbf + (size_t)nc * 64 * 192;
    for (int i = t; i < 1536; i += 256)
      gll16(&src[i * 8], &Wc[buf][i * 8]);
  };

  stageW(0, 0);
  __syncthreads();           // Xn written AND Wc[0] DMA drained
  int cur = 0;
  for (int nc = 0; nc < nchunks; nc++) {
    if (nc + 1 < nchunks) stageW(nc + 1, cur ^ 1);   // overlaps MFMA below
    f32x4 z = {0.f, 0.f, 0.f, 0.f};
    f32x4 acc0 = z, acc1 = z, acc2 = z, acc3 = z;
#pragma unroll
    for (int ks = 0; ks < 6; ks++) {
      int k0 = ks * 32 + grp * 8;
      int gsw = ((((ks << 2) + grp) ^ key) << 3);
      s16x8 a = *(s16x8*)&Xn[(wv * 16 + r) * 200 + k0];
      acc0 = MFMA_BF16(a, *(s16x8*)&Wc[cur][r * 192 + gsw], acc0);
      acc1 = MFMA_BF16(a, *(s16x8*)&Wc[cur][(16 + r) * 192 + gsw], acc1);
      acc2 = MFMA_BF16(a, *(s16x8*)&Wc[cur][(32 + r) * 192 + gsw], acc2);
      acc3 = MFMA_BF16(a, *(s16x8*)&Wc[cur][(48 + r) * 192 + gsw], acc3);
    }
    u16* op = out + ((size_t)b * BPIX + opx0 + wv * 16 + grp * 4) * ostride + nc * 64 + r;
#pragma unroll
    for (int i = 0; i < 4; i++) {
      op[(size_t)i * ostride] = f2bf(acc0[i]);
      op[(size_t)i * ostride + 16] = f2bf(acc1[i]);
      op[(size_t)i * ostride + 32] = f2bf(acc2[i]);
      op[(size_t)i * ostride + 48] = f2bf(acc3[i]);
    }
    __syncthreads();   // Wc[cur] reads done; Wc[cur^1] DMA drained
    cur ^= 1;
  }
}

// ---------------------------------------------------------------------------
// Banded depthwise 3x3 on qkv band buffer [B][BPIX][576] bf16.
// Halo staging via global_load_lds DMA; OOB lanes read a zero page.
// ---------------------------------------------------------------------------
__global__ __launch_bounds__(256, 4)
void k_dw_attn_band(const u16* __restrict__ qb_band, const float* __restrict__ wdw,
                    u16* __restrict__ qkb, u16* __restrict__ vpm,
                    float* __restrict__ ssq, int r0, const u16* __restrict__ zp) {
  __shared__ u16 Hl[6 * 18 * 64];
  __shared__ float sred[8 * 64];
  int t = threadIdx.x;
  int cc = blockIdx.x % 9;
  int rem = blockIdx.x / 9;        // 512 values
  int b = rem >> 6; int r2 = rem & 63;
  int h0l = (r2 >> 3) * 4, w0 = (r2 & 7) * 16;   // band-local interior row, col
  int c0 = cc * 64;
  const s16x8 z8 = {0, 0, 0, 0, 0, 0, 0, 0};
  for (int i = t; i < 864; i += 256) {
    int px = i >> 3, sg = i & 7;
    int hh = px / 18, ww = px % 18;
    int slot = h0l + hh;                 // in [0, 34)
    int gh = r0 - 1 + slot;
    int gw = w0 - 1 + ww;
    const void* g = (gh >= 0 && gh < NH && gw >= 0 && gw < NW)
        ? (const void*)&qb_band[((size_t)b * BPIX + slot * NW + gw) * NQ + c0 + sg * 8]
        : (const void*)zp;
    gll16(g, &Hl[i * 8]);
  }
  __syncthreads();
  int cp = t & 31, psub = t >> 5;
  int pr = psub >> 1, pc0 = (psub & 1) * 8;
  int gc = c0 + 2 * cp;
  float wg0[9], wg1[9];
#pragma unroll
  for (int q = 0; q < 9; q++) { wg0[q] = wdw[gc * 9 + q]; wg1[q] = wdw[(gc + 1) * 9 + q]; }
  bool isv = (c0 >= 384);
  float sq0 = 0.f, sq1 = 0.f;
  s16x8 ov0 = z8, ov1 = z8;
#pragma unroll
  for (int j = 0; j < 8; j++) {
    int pc = pc0 + j;
    float a0 = 0.f, a1 = 0.f;
#pragma unroll
    for (int dr = 0; dr < 3; dr++)
#pragma unroll
      for (int dc = 0; dc < 3; dc++) {
        unsigned u = *(const unsigned*)&Hl[((pr + dr) * 18 + pc + dc) * 64 + 2 * cp];
        a0 = fmaf(lo2f(u), wg0[dr * 3 + dc], a0);
        a1 = fmaf(hi2f(u), wg1[dr * 3 + dc], a1);
      }
    u16 u0 = f2bf(a0), u1 = f2bf(a1);
    if (isv) {
      int gp = (r0 + h0l + pr) * NW + w0 + pc;   // global pixel
      *(unsigned*)&vpm[((size_t)b * HW + gp) * 192 + (gc - 384)] =
          (unsigned)u0 | ((unsigned)u1 << 16);
    } else {
      ov0[j] = (short)u0; ov1[j] = (short)u1;
      float f0 = bf2f(u0), f1 = bf2f(u1);
      sq0 = fmaf(f0, f0, sq0); sq1 = fmaf(f1, f1, sq1);
    }
  }
  if (!isv) {
    int lpx = (h0l + pr) * NW + w0 + pc0;        // band-local pixel
    *(s16x8*)&qkb[((size_t)b * 384 + gc) * BIPIX + lpx] = ov0;
    *(s16x8*)&qkb[((size_t)b * 384 + gc + 1) * BIPIX + lpx] = ov1;
    sred[psub * 64 + 2 * cp] = sq0;
    sred[psub * 64 + 2 * cp + 1] = sq1;
    __syncthreads();
    if (t < 64) {
      float sa = 0.f;
#pragma unroll
      for (int p8 = 0; p8 < 8; p8++) sa += sred[p8 * 64 + t];
      atomicAdd(&ssq[b * 384 + c0 + t], sa);
    }
  }
}

// ---------------------------------------------------------------------------
// attn_raw[b,h,c,d] += sum_{band px} q[c,px]*k[d,px]  (MFMA, K split 4 ways)
// ---------------------------------------------------------------------------
__global__ __launch_bounds__(256, 2)
void k_attn_band(const u16* __restrict__ qkb, float* __restrict__ attn) {
  __shared__ float par[4 * 2304];
  int t = threadIdx.x;
  int lane = t & 63, wv = t >> 6;
  int r = lane & 15, grp = lane >> 4;
  int bh = blockIdx.x >> 2, kc = blockIdx.x & 3;
  int b = bh >> 2, h = bh & 3;
  const u16* qb = qkb + ((size_t)b * 384 + h * 48) * BIPIX;
  const u16* kb = qkb + ((size_t)b * 384 + 192 + h * 48) * BIPIX;
  f32x4 z = {0.f, 0.f, 0.f, 0.f};
  f32x4 acc[3][3];
#pragma unroll
  for (int i = 0; i < 3; i++)
#pragma unroll
    for (int j = 0; j < 3; j++) acc[i][j] = z;
  int kbase = kc * 1024 + wv * 256 + grp * 8;
#pragma unroll 2
  for (int ks = 0; ks < 8; ks++) {
    int k0 = kbase + ks * 32;
    s16x8 af[3], bf[3];
#pragma unroll
    for (int mt = 0; mt < 3; mt++) af[mt] = *(const s16x8*)&qb[(size_t)(mt * 16 + r) * BIPIX + k0];
#pragma unroll
    for (int nt = 0; nt < 3; nt++) bf[nt] = *(const s16x8*)&kb[(size_t)(nt * 16 + r) * BIPIX + k0];
#pragma unroll
    for (int mt = 0; mt < 3; mt++)
#pragma unroll
      for (int nt = 0; nt < 3; nt++) acc[mt][nt] = MFMA_BF16(af[mt], bf[nt], acc[mt][nt]);
  }
#pragma unroll
  for (int mt = 0; mt < 3; mt++)
#pragma unroll
    for (int nt = 0; nt < 3; nt++)
#pragma unroll
      for (int i = 0; i < 4; i++)
        par[wv * 2304 + (mt * 16 + grp * 4 + i) * 48 + nt * 16 + r] = acc[mt][nt][i];
  __syncthreads();
  float* ag = attn + (size_t)bh * 2304;
  for (int i = t; i < 2304; i += 256)
    atomicAdd(&ag[i], par[i] + par[2304 + i] + par[4608 + i] + par[6912 + i]);
}

// ---------------------------------------------------------------------------
// Softmax over d with q/k norms, scale, temp; fold v_gate in (in place)
// ---------------------------------------------------------------------------
__global__ void k_softmax(float* __restrict__ attn, const float* __restrict__ ssq,
                          const float* __restrict__ tempt, const float* __restrict__ vg) {
  int bh = blockIdx.x, b = bh >> 2, h = bh & 3;
  int t = threadIdx.x;  // 64
  __shared__ float srk[48], svg[48];
  if (t < 48) {
    float nk = sqrtf(ssq[b * 384 + 192 + h * 48 + t]);
    srk[t] = 1.f / fmaxf(nk, 1e-12f);
    svg[t] = vg[b * 192 + h * 48 + t];
  }
  __syncthreads();
  if (t < 48) {
    float nq = sqrtf(ssq[b * 384 + h * 48 + t]);
    float rq = 1.f / fmaxf(nq, 1e-12f);
    float sc = 0.14433756729740643f * tempt[b * 4 + h] * rq;
    float* row = attn + (size_t)bh * 2304 + t * 48;
    float l[48]; float mx = -1e30f;
#pragma unroll
    for (int d = 0; d < 48; d++) { l[d] = row[d] * srk[d] * sc; mx = fmaxf(mx, l[d]); }
    float ss = 0.f;
#pragma unroll
    for (int d = 0; d < 48; d++) { l[d] = expf(l[d] - mx); ss += l[d]; }
    float inv = 1.f / ss;
#pragma unroll
    for (int d = 0; d < 48; d++) row[d] = l[d] * inv * svg[d];
  }
}

// ---------------------------------------------------------------------------
// W_D[b] = [ w_proj @ blockdiag(attn') | w_proj ]  (192 x 384 bf16 per batch)
// ---------------------------------------------------------------------------
__global__ __launch_bounds__(256)
void k_wd(const float* __restrict__ attn, const float* __restrict__ wp,
          u16* __restrict__ wdg) {
  __shared__ float am[4 * 48 * 48];
  int b = blockIdx.x >> 3, oc = blockIdx.x & 7;
  int t = threadIdx.x;
  const float* ag = attn + (size_t)b * 4 * 2304;
  for (int i = t; i < 9216; i += 256) am[i] = ag[i];
  __syncthreads();
  u16* wdb = wdg + (size_t)b * 192 * 384;
  for (int idx = t; idx < 24 * 384; idx += 256) {
    int oo = idx / 384, j = idx % 384;
    int o = oc * 24 + oo;
    float val;
    if (j < 192) {
      int hj = j / 48, dj = j % 48;
      const float* wpo = wp + o * 192 + hj * 48;
      const float* ap = am + hj * 2304 + dj;
      float sa = 0.f;
#pragma unroll
      for (int c = 0; c < 48; c++) sa = fmaf(wpo[c], ap[c * 48], sa);
      val = sa;
    } else {
      val = wp[o * 192 + (j - 192)];
    }
    wdb[o * 384 + j] = f2bf(val);
  }
}

// ---------------------------------------------------------------------------
// x2 = x + W_D @ [v ; dwconv3x3_local(v)] per 4x16 pixel tile (MFMA, K=384)
// DMA double-buffered halo staging (R4).  NEW: the 48 x-residual loads are
// issued after the dwconv loop and PINNED in VGPRs via empty asm (R3 showed
// the compiler sinks unpinned loads to the epilogue), so the 100 MB x-stream
// overlaps the MFMA phase instead of serializing at the tail.
// ---------------------------------------------------------------------------
__global__ __launch_bounds__(256, 2)
void k_proj(const u16* __restrict__ vpm, const float* __restrict__ wl,
            const u16* __restrict__ wdg, const float* __restrict__ x,
            float* __restrict__ x2, const u16* __restrict__ zp) {
  __shared__ u16 Hl[2][6 * 18 * 64];
  __shared__ u16 Xl[64 * 392];
  int t = threadIdx.x;
  int b = blockIdx.x >> 8; int r2 = blockIdx.x & 255;
  int h0 = (r2 >> 3) * 4, w0 = (r2 & 7) * 16;
  int cp = t & 31, psub = t >> 5;
  int pr = psub >> 1, pc0 = (psub & 1) * 8;
  int lane = t & 63, wv = t >> 6;
  int r = lane & 15, grp = lane >> 4;

  auto stageH = [&](int c3s, int buf) {
    int c0s = c3s * 64;
    for (int i = t; i < 864; i += 256) {
      int px = i >> 3, sg = i & 7;
      int hh = px / 18, ww = px % 18;
      int gh = h0 - 1 + hh, gw = w0 - 1 + ww;
      const void* g = (gh >= 0 && gh < NH && gw >= 0 && gw < NW)
          ? (const void*)&vpm[((size_t)b * HW + gh * NW + gw) * 192 + c0s + sg * 8]
          : (const void*)zp;
      gll16(g, &Hl[buf][i * 8]);
    }
  };

  stageH(0, 0);
  __syncthreads();           // drains DMA: Hl[0] ready
  int cur = 0;
  for (int c3 = 0; c3 < 3; c3++) {
    if (c3 < 2) stageH(c3 + 1, cur ^ 1);   // DMA overlaps dwconv below
    int c0 = c3 * 64;
    int gc = c0 + 2 * cp;
    float wg0[9], wg1[9];
#pragma unroll
    for (int q = 0; q < 9; q++) { wg0[q] = wl[gc * 9 + q]; wg1[q] = wl[(gc + 1) * 9 + q]; }
#pragma unroll
    for (int j = 0; j < 8; j++) {
      int pc = pc0 + j; int p = pr * 16 + pc;
      float a0 = 0.f, a1 = 0.f; unsigned uc = 0;
#pragma unroll
      for (int dr = 0; dr < 3; dr++)
#pragma unroll
        for (int dc = 0; dc < 3; dc++) {
          unsigned u = *(const unsigned*)&Hl[cur][((pr + dr) * 18 + pc + dc) * 64 + 2 * cp];
          if (dr == 1 && dc == 1) uc = u;
          a0 = fmaf(lo2f(u), wg0[dr * 3 + dc], a0);
          a1 = fmaf(hi2f(u), wg1[dr * 3 + dc], a1);
        }
      *(unsigned*)&Xl[p * 392 + gc] = uc;
      *(unsigned*)&Xl[p * 392 + 192 + gc] =
          (unsigned)f2bf(a0) | ((unsigned)f2bf(a1) << 16);
    }
    __syncthreads();  // all reads of Hl[cur] done; DMA into Hl[cur^1] drained
    cur ^= 1;
  }
  // issue residual loads NOW and pin them: stream overlaps the MFMA phase
  float xres[3][4][4];
#pragma unroll
  for (int mt = 0; mt < 3; mt++)
#pragma unroll
    for (int nt = 0; nt < 4; nt++) {
      size_t base = ((size_t)b * NC + wv * 48 + mt * 16 + grp * 4) * HW +
                    (h0 + nt) * NW + w0 + r;
#pragma unroll
      for (int i = 0; i < 4; i++) xres[mt][nt][i] = x[base + (size_t)i * HW];
    }
#pragma unroll
  for (int mt = 0; mt < 3; mt++)
#pragma unroll
    for (int nt = 0; nt < 4; nt++)
#pragma unroll
      for (int i = 0; i < 4; i++)
        asm volatile("" : "+v"(xres[mt][nt][i]));

  const u16* wdb = wdg + (size_t)b * 192 * 384;
  f32x4 z = {0.f, 0.f, 0.f, 0.f};
  f32x4 acc[3][4];
#pragma unroll
  for (int i = 0; i < 3; i++)
#pragma unroll
    for (int j = 0; j < 4; j++) acc[i][j] = z;
#pragma unroll 2
  for (int ks = 0; ks < 12; ks++) {
    int k0 = ks * 32 + grp * 8;
    s16x8 b0 = *(s16x8*)&Xl[r * 392 + k0];
    s16x8 b1 = *(s16x8*)&Xl[(16 + r) * 392 + k0];
    s16x8 b2 = *(s16x8*)&Xl[(32 + r) * 392 + k0];
    s16x8 b3 = *(s16x8*)&Xl[(48 + r) * 392 + k0];
#pragma unroll
    for (int mt = 0; mt < 3; mt++) {
      s16x8 a = *(const s16x8*)&wdb[(size_t)(wv * 48 + mt * 16 + r) * 384 + k0];
      acc[mt][0] = MFMA_BF16(a, b0, acc[mt][0]);
      acc[mt][1] = MFMA_BF16(a, b1, acc[mt][1]);
      acc[mt][2] = MFMA_BF16(a, b2, acc[mt][2]);
      acc[mt][3] = MFMA_BF16(a, b3, acc[mt][3]);
    }
  }
#pragma unroll
  for (int mt = 0; mt < 3; mt++)
#pragma unroll
    for (int nt = 0; nt < 4; nt++) {
      size_t base = ((size_t)b * NC + wv * 48 + mt * 16 + grp * 4) * HW +
                    (h0 + nt) * NW + w0 + r;
#pragma unroll
      for (int i = 0; i < 4; i++) {
        size_t idx = base + (size_t)i * HW;
        x2[idx] = acc[mt][nt][i] + xres[mt][nt][i];
      }
    }
}

// ---------------------------------------------------------------------------
// FUSED: depthwise 3x3 + GELU gating + ffn_out GEMM + residual, per band.
// DMA double-buffered H1/H2 halo staging (R4).  x2 residual loaded at use
// (R3's early-load variant regressed ~60us from register pressure).
// ---------------------------------------------------------------------------
__global__ __launch_bounds__(256, 2)
void k_gelu_ffn_band(const u16* __restrict__ ypre, const float* __restrict__ wdwf,
                     const u16* __restrict__ wfo, const float* __restrict__ x2,
                     float* __restrict__ out, int r0, const u16* __restrict__ zp) {
  __shared__ u16 H1[2][6 * 18 * 64];
  __shared__ u16 H2[2][6 * 18 * 72];
  __shared__ u16 Yc[64 * 80];       // ypm chunk: 64 px x 64 j (stride 80 for banks)
  int t = threadIdx.x;
  int b = blockIdx.x >> 6; int r2 = blockIdx.x & 63;
  int h0l = (r2 >> 3) * 4, w0 = (r2 & 7) * 16;
  int cp = t & 31, psub = t >> 5;
  int pr = psub >> 1, pc0 = (psub & 1) * 8;
  int lane = t & 63, wv = t >> 6;
  int r = lane & 15, grp = lane >> 4;
  int jl = 2 * cp;

  auto stage = [&](int jc, int buf) {
    int j0s = jc * 64;
    int base2 = j0s + 504;
    for (int i = t; i < 864; i += 256) {
      int px = i >> 3, sg = i & 7;
      int hh = px / 18, ww = px % 18;
      int slot = h0l + hh;
      int gh = r0 - 1 + slot, gw = w0 - 1 + ww;
      const void* g = (gh >= 0 && gh < NH && gw >= 0 && gw < NW)
          ? (const void*)&ypre[((size_t)b * BPIX + slot * NW + gw) * NG2P + j0s + sg * 8]
          : (const void*)zp;
      gll16(g, &H1[buf][i * 8]);
    }
    for (int i = t; i < 972; i += 256) {
      int px = i / 9, sg = i - px * 9;
      int hh = px / 18, ww = px % 18;
      int slot = h0l + hh;
      int gh = r0 - 1 + slot, gw = w0 - 1 + ww;
      const void* g = (gh >= 0 && gh < NH && gw >= 0 && gw < NW)
          ? (const void*)&ypre[((size_t)b * BPIX + slot * NW + gw) * NG2P + base2 + sg * 8]
          : (const void*)zp;
      gll16(g, &H2[buf][i * 8]);
    }
  };

  f32x4 z = {0.f, 0.f, 0.f, 0.f};
  f32x4 acc[3][4];
#pragma unroll
  for (int i = 0; i < 3; i++)
#pragma unroll
    for (int j = 0; j < 4; j++) acc[i][j] = z;

  stage(0, 0);
  __syncthreads();           // H[0] ready
  int cur = 0;
  for (int jc = 0; jc < 8; jc++) {
    if (jc < 7) stage(jc + 1, cur ^ 1);   // DMA overlaps dwconv+gelu below
    int j0 = jc * 64;
    int j = j0 + jl;
    bool v0 = (j < NHID), v1 = (j + 1 < NHID);
    float w1a[9], w1b[9], w2a[9], w2b[9];
#pragma unroll
    for (int q = 0; q < 9; q++) {
      w1a[q] = 0.f; w1b[q] = 0.f; w2a[q] = 0.f; w2b[q] = 0.f;
      if (v0) { w1a[q] = wdwf[j * 9 + q]; w2a[q] = wdwf[(j + NHID) * 9 + q]; }
      if (v1) { w1b[q] = wdwf[(j + 1) * 9 + q]; w2b[q] = wdwf[(j + 1 + NHID) * 9 + q]; }
    }
#pragma unroll
    for (int jj = 0; jj < 8; jj++) {
      int pc = pc0 + jj;
      float d1a = 0.f, d1b = 0.f, d2a = 0.f, d2b = 0.f;
#pragma unroll
      for (int dr = 0; dr < 3; dr++)
#pragma unroll
        for (int dc = 0; dc < 3; dc++) {
          int q = dr * 3 + dc;
          unsigned u1 = *(const unsigned*)&H1[cur][((pr + dr) * 18 + pc + dc) * 64 + jl];
          unsigned u2 = *(const unsigned*)&H2[cur][((pr + dr) * 18 + pc + dc) * 72 + jl + 6];
          d1a = fmaf(lo2f(u1), w1a[q], d1a); d1b = fmaf(hi2f(u1), w1b[q], d1b);
          d2a = fmaf(lo2f(u2), w2a[q], d2a); d2b = fmaf(hi2f(u2), w2b[q], d2b);
        }
      float ga = 0.5f * d1a * (1.f + erff(d1a * 0.70710678118654752f));
      float gb = 0.5f * d1b * (1.f + erff(d1b * 0.70710678118654752f));
      float ya = v0 ? ga * d2a : 0.f;
      float yb = v1 ? gb * d2b : 0.f;
      int lp = pr * 16 + pc;           // local px 0..63
      *(unsigned*)&Yc[lp * 80 + jl] = (unsigned)f2bf(ya) | ((unsigned)f2bf(yb) << 16);
    }
    __syncthreads();   // Yc ready; DMA for cur^1 drained here too
#pragma unroll
    for (int ks = 0; ks < 2; ks++) {
      int k0 = ks * 32 + grp * 8;
      s16x8 b0 = *(s16x8*)&Yc[r * 80 + k0];
      s16x8 b1 = *(s16x8*)&Yc[(16 + r) * 80 + k0];
      s16x8 b2 = *(s16x8*)&Yc[(32 + r) * 80 + k0];
      s16x8 b3 = *(s16x8*)&Yc[(48 + r) * 80 + k0];
#pragma unroll
      for (int mt = 0; mt < 3; mt++) {
        s16x8 a = *(const s16x8*)&wfo[(size_t)(wv * 48 + mt * 16 + r) * NHIDP + j0 + k0];
        acc[mt][0] = MFMA_BF16(a, b0, acc[mt][0]);
        acc[mt][1] = MFMA_BF16(a, b1, acc[mt][1]);
        acc[mt][2] = MFMA_BF16(a, b2, acc[mt][2]);
        acc[mt][3] = MFMA_BF16(a, b3, acc[mt][3]);
      }
    }
    __syncthreads();   // Yc consumed; safe to overwrite next iter
    cur ^= 1;
  }
  // epilogue: out = acc + x2
#pragma unroll
  for (int mt = 0; mt < 3; mt++)
#pragma unroll
    for (int nt = 0; nt < 4; nt++) {
      size_t base = ((size_t)b * NC + wv * 48 + mt * 16 + grp * 4) * HW +
                    (r0 + h0l + nt) * NW + w0 + r;
#pragma unroll
      for (int i = 0; i < 4; i++) {
        size_t idx = base + (size_t)i * HW;
        out[idx] = acc[mt][nt][i] + x2[idx];
      }
    }
}

// ---------------------------------------------------------------------------
extern "C" void kernel_launch(void* const* d_in, const int* in_sizes, int n_in,
                              void* d_out, int out_size, void* d_ws, size_t ws_size,
                              hipStream_t stream) {
  const float* x      = (const float*)d_in[0];
  const float* ce     = (const float*)d_in[1];
  const float* ln1w   = (const float*)d_in[2];
  const float* ln1b   = (const float*)d_in[3];
  const float* ln2w   = (const float*)d_in[4];
  const float* ln2b   = (const float*)d_in[5];
  const float* wqkv   = (const float*)d_in[6];
  const float* wqkvdw = (const float*)d_in[7];
  const float* wproj  = (const float*)d_in[8];
  const float* btemp  = (const float*)d_in[9];
  const float* taw1   = (const float*)d_in[10];
  const float* tab1   = (const float*)d_in[11];
  const float* taw2   = (const float*)d_in[12];
  const float* tab2   = (const float*)d_in[13];
  const float* vgw    = (const float*)d_in[14];
  const float* vgb    = (const float*)d_in[15];
  const float* wlocal = (const float*)d_in[16];
  const float* wffni  = (const float*)d_in[17];
  const float* wffndw = (const float*)d_in[18];
  const float* wffno  = (const float*)d_in[19];
  float* outp = (float*)d_out;
  char* ws = (char*)d_ws;

  // workspace layout (bytes), peak 224,602,240 + 256 zero page
  const size_t REQUIRED = 224602496ULL;
  if (ws_size < REQUIRED) {  // diagnosable failure mode instead of a fault
    hipMemsetAsync(d_out, 0, (size_t)out_size * 4, stream);
    return;
  }
  u16*   wq_bf   = (u16*)(ws + 0);            // 221184
  u16*   wfi_bf  = (u16*)(ws + 221184);       // 393216
  u16*   wfo_bf  = (u16*)(ws + 614400);       // 196608
  float* tempt   = (float*)(ws + 811008);     // 128
  float* vg      = (float*)(ws + 811136);     // 6144
  float* ssq     = (float*)(ws + 817280);     // 12288
  float* attn    = (float*)(ws + 829568);     // 294912
  u16*   wdg     = (u16*)(ws + 1124480);      // 1179648
  u16*   qkvband = (u16*)(ws + 2304128);      // 40108032 (8*4352*576*2)
  u16*   qkband  = (u16*)(ws + 42412160);     // 25165824 (8*384*4096*2)
  u16*   ypreband= (u16*)(ws + 2304128);      // 71303168 (8*4352*1024*2) reuses qkv+qk
  u16*   vpm     = (u16*)(ws + 73607296);     // 50331648 (8*16384*192*2)
  float* x2      = (float*)(ws + 123938944);  // 100663296
  u16*   zp      = (u16*)(ws + 224602240);    // 256 zero page for OOB DMA lanes

  hipMemsetAsync(ws + 817280, 0, 12288 + 294912, stream);  // ssq + attn_raw
  hipMemsetAsync(ws + 224602240, 0, 256, stream);          // zero page
  k_prep<<<512, 256, 0, stream>>>(wqkv, wffni, wffno, wq_bf, wfi_bf, wfo_bf);
  k_ctx<<<8, 256, 0, stream>>>(ce, taw1, tab1, taw2, tab2, vgw, vgb, btemp, tempt, vg);

  for (int band = 0; band < 4; band++) {
    int r0 = band * BROWS;
    int rs = (r0 > 0) ? r0 - 1 : 0;
    int re = (r0 + BROWS + 1 < NH) ? r0 + BROWS + 1 : NH;
    int nr = re - rs;
    int s0 = rs - (r0 - 1);
    k_ln_gemm_band<<<8 * nr * 2, 256, 0, stream>>>(x, ln1w, ln1b, wq_bf, qkvband, 9, rs, s0);
    k_dw_attn_band<<<9 * 8 * 64, 256, 0, stream>>>(qkvband, wqkvdw, qkband, vpm, ssq, r0, zp);
    k_attn_band<<<32 * 4, 256, 0, stream>>>(qkband, attn);
  }
  k_softmax<<<32, 64, 0, stream>>>(attn, ssq, tempt, vg);
  k_wd<<<64, 256, 0, stream>>>(attn, wproj, wdg);
  k_proj<<<2048, 256, 0, stream>>>(vpm, wlocal, wdg, x, x2, zp);

  for (int band = 0; band < 4; band++) {
    int r0 = band * BROWS;
    int rs = (r0 > 0) ? r0 - 1 : 0;
    int re = (r0 + BROWS + 1 < NH) ? r0 + BROWS + 1 : NH;
    int nr = re - rs;
    int s0 = rs - (r0 - 1);
    k_ln_gemm_band<<<8 * nr * 2, 256, 0, stream>>>(x2, ln2w, ln2b, wfi_bf, ypreband, 16, rs, s0);
    k_gelu_ffn_band<<<8 * 64, 256, 0, stream>>>(ypreband, wffndw, wfo_bf, x2, outp, r0, zp);
  }
}